// Round 9
// baseline (481.384 us; speedup 1.0000x reference)
//
#include <hip/hip_runtime.h>
#include <hip/hip_bf16.h>

// ---------------------------------------------------------------------------
// DiT block, bf16 MFMA, round 16.
// Recombination: r15's templated GEMM (measured better: 67.3us vs 70us, the
// compile-time LDA/LDB strength-reduces staging address math) + r13's
// RUNTIME-stride attention (r15's templated attn made KVT a constant ->
// compiler unrolled a 3-barrier 50-MFMA loop body -> +15us regression).
// Everything else unchanged (XCD swizzles, split-K W2, zero-conflict LDS).
// ---------------------------------------------------------------------------

#define D_EMB 768
#define N_HEADS 12
#define HEAD 64
#define B_SZ 8
#define T_IMG 1024
#define T_CTX 256
#define FF_DIM 3072
#define ROWS_IMG (B_SZ * T_IMG)      // 8192
#define ROWS_CTX (B_SZ * T_CTX)     // 2048
#define BIGCOL (1 << 28)
#define PART_STRIDE (ROWS_IMG * D_EMB)   // split-K partial stride (elems)

typedef __bf16 bf16x8 __attribute__((ext_vector_type(8)));
typedef __bf16 bf16x4 __attribute__((ext_vector_type(4)));
typedef float f32x4 __attribute__((ext_vector_type(4)));

__device__ __forceinline__ void gld16(const void* g, void* l) {
    __builtin_amdgcn_global_load_lds(
        (const __attribute__((address_space(1))) unsigned int*)g,
        (__attribute__((address_space(3))) unsigned int*)l, 16, 0, 0);
}

// ---------------- fp32 -> bf16 convert (ctx) ----------------
__global__ __launch_bounds__(256) void cvt_bf16_kernel(const float* __restrict__ src,
                                                       __bf16* __restrict__ dst, int n4) {
    int i = blockIdx.x * 256 + threadIdx.x;
    if (i >= n4) return;
    float4 v = ((const float4*)src)[i];
    __bf16* d = dst + i * 4;
    d[0] = (__bf16)v.x; d[1] = (__bf16)v.y; d[2] = (__bf16)v.z; d[3] = (__bf16)v.w;
}

// ---------------- W2 split-K reduce: X += P0 + P1 + b2 ----------------
__global__ __launch_bounds__(256) void reduce_w2_kernel(
    const __bf16* __restrict__ P, const float* __restrict__ b2,
    float* __restrict__ X) {
    int i = blockIdx.x * 256 + threadIdx.x;
    int base = i * 4;
    int col = base % D_EMB;
    bf16x4 p0 = *(const bf16x4*)&P[base];
    bf16x4 p1 = *(const bf16x4*)&P[PART_STRIDE + base];
    float4 x = *(float4*)&X[base];
    float4 bb = *(const float4*)&b2[col];
    x.x += (float)p0[0] + (float)p1[0] + bb.x;
    x.y += (float)p0[1] + (float)p1[1] + bb.y;
    x.z += (float)p0[2] + (float)p1[2] + bb.z;
    x.w += (float)p0[3] + (float)p1[3] + bb.w;
    *(float4*)&X[base] = x;
}

// ---------------- tiled transpose fp32 -> bf16: dst[c][r] = src[r][c] -------
__global__ __launch_bounds__(256) void transpose_cvt_kernel(
    const float* __restrict__ src, __bf16* __restrict__ dst,
    int src_rows, int src_cols) {
    __shared__ float tile[64][65];
    int tid = threadIdx.x;
    int r0 = blockIdx.y * 64, c0 = blockIdx.x * 64;
    int lr = tid >> 4, lc = (tid & 15) * 4;
#pragma unroll
    for (int i = 0; i < 4; i++) {
        float4 v = *(const float4*)&src[(size_t)(r0 + i * 16 + lr) * src_cols + c0 + lc];
        tile[i * 16 + lr][lc] = v.x; tile[i * 16 + lr][lc + 1] = v.y;
        tile[i * 16 + lr][lc + 2] = v.z; tile[i * 16 + lr][lc + 3] = v.w;
    }
    __syncthreads();
#pragma unroll
    for (int i = 0; i < 4; i++) {
        int cc = i * 16 + lr;
        int rr = (tid & 15) * 4;
        bf16x4 o;
#pragma unroll
        for (int j = 0; j < 4; j++) o[j] = (__bf16)tile[rr + j][cc];
        *(bf16x4*)&dst[(size_t)(c0 + cc) * src_rows + r0 + rr] = o;
    }
}

// ---------------- repack per-head qkv weights -> transposed bf16 [2304][768]
__global__ __launch_bounds__(256) void repack_qkv_t_kernel(
    const float* __restrict__ Wq, const float* __restrict__ Wk, const float* __restrict__ Wv,
    const float* __restrict__ bq, const float* __restrict__ bk, const float* __restrict__ bv,
    __bf16* __restrict__ Wt, float* __restrict__ bp) {
    __shared__ float tile[64][65];
    int tid = threadIdx.x;
    int which = blockIdx.y / 12, h = blockIdx.y - which * 12;
    int d0 = blockIdx.x * 64;
    const float* W = (which == 0) ? Wq : ((which == 1) ? Wk : Wv);
    const float* src = W + ((size_t)h * D_EMB + d0) * HEAD;
    int lr = tid >> 4, lc = (tid & 15) * 4;
#pragma unroll
    for (int i = 0; i < 4; i++) {
        float4 v = *(const float4*)&src[(size_t)(i * 16 + lr) * HEAD + lc];
        tile[i * 16 + lr][lc] = v.x; tile[i * 16 + lr][lc + 1] = v.y;
        tile[i * 16 + lr][lc + 2] = v.z; tile[i * 16 + lr][lc + 3] = v.w;
    }
    __syncthreads();
#pragma unroll
    for (int i = 0; i < 4; i++) {
        int e = i * 16 + lr;
        int dd = (tid & 15) * 4;
        bf16x4 o;
#pragma unroll
        for (int j = 0; j < 4; j++) o[j] = (__bf16)tile[dd + j][e];
        *(bf16x4*)&Wt[(size_t)(which * 768 + h * 64 + e) * D_EMB + d0 + dd] = o;
    }
    if (blockIdx.x == 0 && tid < 64) {
        const float* bb = (which == 0) ? bq : ((which == 1) ? bk : bv);
        bp[which * 768 + h * 64 + tid] = bb[h * 64 + tid];
    }
}

// ---------------- layernorm over 768, bf16 output ----------------
__global__ __launch_bounds__(256) void ln_kernel(const float* __restrict__ x,
                                                 const float* __restrict__ lw,
                                                 const float* __restrict__ lb,
                                                 __bf16* __restrict__ y) {
    int row = blockIdx.x;
    int tid = threadIdx.x;
    const float* xr = x + (size_t)row * D_EMB;
    float a0 = xr[tid], a1 = xr[tid + 256], a2 = xr[tid + 512];
    float s = a0 + a1 + a2;
    float ss = a0 * a0 + a1 * a1 + a2 * a2;
#pragma unroll
    for (int off = 32; off > 0; off >>= 1) {
        s += __shfl_down(s, off, 64);
        ss += __shfl_down(ss, off, 64);
    }
    __shared__ float red[8];
    __shared__ float stats[2];
    int wv = tid >> 6, lane = tid & 63;
    if (lane == 0) { red[wv] = s; red[4 + wv] = ss; }
    __syncthreads();
    if (tid == 0) {
        float S = red[0] + red[1] + red[2] + red[3];
        float SS = red[4] + red[5] + red[6] + red[7];
        float mu = S * (1.0f / D_EMB);
        float var = SS * (1.0f / D_EMB) - mu * mu;
        stats[0] = mu;
        stats[1] = rsqrtf(var + 1e-5f);
    }
    __syncthreads();
    float mu = stats[0], rs = stats[1];
    __bf16* yr = y + (size_t)row * D_EMB;
    yr[tid]       = (__bf16)((a0 - mu) * rs * lw[tid]       + lb[tid]);
    yr[tid + 256] = (__bf16)((a1 - mu) * rs * lw[tid + 256] + lb[tid + 256]);
    yr[tid + 512] = (__bf16)((a2 - mu) * rs * lw[tid + 512] + lb[tid + 512]);
}

// ---------------- bf16 MFMA GEMM (B^T layout), swapped operands, 128² -------
// BK=64, XOR-swizzled LDS (zero bank conflicts), XCD grouping swizzle,
// optional split-K via blockIdx.z, COMPILE-TIME strides LDA/LDB.
__device__ __forceinline__ bf16x8 lds_frag(const __bf16* h, int row, int kk, int quad) {
    int off = (kk * 32 + quad * 8) ^ ((row & 7) << 3);    // swizzled read
    return *(const bf16x8*)&h[row * 64 + off];
}

template <int LDA, int LDB>
__global__ __launch_bounds__(256) void mfma_gemm_bt(
    const __bf16* __restrict__ A,
    const __bf16* __restrict__ Bt,
    const float* __restrict__ bias,
    __bf16* __restrict__ Cb, int ldc,
    int Kc, int act, int qlimit,
    __bf16* __restrict__ VTout, int vtok, int vcol0, int kcol0, int kcol1,
    float* __restrict__ Xres) {
    __shared__ __bf16 As[128 * 64];   // 16 KiB
    __shared__ __bf16 Bs[128 * 64];   // 16 KiB
    int tid = threadIdx.x;
    int kz = blockIdx.z;
    // bijective XCD grouping swizzle (requires nwg%8==0; true for all grids):
    // blocks sharing an A row-panel (same by) land on the same XCD's L2.
    int gx = gridDim.x;
    int nwg = gx * gridDim.y;
    int orig = blockIdx.y * gx + blockIdx.x;
    int swz = (orig & 7) * (nwg >> 3) + (orig >> 3);
    int bx = swz % gx, by = swz / gx;

    int w = tid >> 6, lane = tid & 63;
    int c = lane & 15, quad = lane >> 4;
    int wm = (w >> 1) * 64, wn = (w & 1) * 64;

    f32x4 acc[4][4];
#pragma unroll
    for (int i = 0; i < 4; i++)
#pragma unroll
        for (int j = 0; j < 4; j++) acc[i][j] = (f32x4){0.f, 0.f, 0.f, 0.f};

    // staging: 256 threads x 4 x 16B per operand tile (128 rows x 64 cols).
    // source col pre-swizzled with the row-XOR so linear LDS + swizzled read
    // = identity (verified r8-r15, 0 conflicts).
    int srow = tid >> 3;                                   // 0..31
    int scol = ((tid & 7) * 8) ^ ((srow & 7) * 8);         // inverse swizzle
    const __bf16* Ag = A + (size_t)(by * 128 + srow) * LDA + (size_t)kz * Kc + scol;
    const __bf16* Bg = Bt + (size_t)(bx * 128 + srow) * LDB + (size_t)kz * Kc + scol;
    char* AsB = (char*)As + w * 1024;
    char* BsB = (char*)Bs + w * 1024;

    for (int k0 = 0; k0 < Kc; k0 += 64) {
#pragma unroll
        for (int j = 0; j < 4; j++) {
            gld16(Ag + (size_t)(j * 32) * LDA + k0, AsB + j * 4096);
            gld16(Bg + (size_t)(j * 32) * LDB + k0, BsB + j * 4096);
        }
        __syncthreads();
#pragma unroll
        for (int kk = 0; kk < 2; kk++) {
            bf16x8 af[4], bfr[4];
#pragma unroll
            for (int mi = 0; mi < 4; mi++)
                af[mi] = lds_frag(As, wm + mi * 16 + c, kk, quad);
#pragma unroll
            for (int ni = 0; ni < 4; ni++)
                bfr[ni] = lds_frag(Bs, wn + ni * 16 + c, kk, quad);
#pragma unroll
            for (int mi = 0; mi < 4; mi++)
#pragma unroll
                for (int ni = 0; ni < 4; ni++)
                    acc[mi][ni] = __builtin_amdgcn_mfma_f32_16x16x32_bf16(
                        bfr[ni], af[mi], acc[mi][ni], 0, 0, 0);   // swapped: C^T
        }
        __syncthreads();
    }

#pragma unroll
    for (int mi = 0; mi < 4; mi++) {
#pragma unroll
        for (int ni = 0; ni < 4; ni++) {
            int row = by * 128 + wm + mi * 16 + c;                 // C row
            int colbase = bx * 128 + wn + ni * 16 + quad * 4;      // 4 consecutive C cols
            float bvv[4] = {0.f, 0.f, 0.f, 0.f};
            if (bias && kz == 0) {
                float4 b4 = *(const float4*)&bias[colbase];
                bvv[0] = b4.x; bvv[1] = b4.y; bvv[2] = b4.z; bvv[3] = b4.w;
            }
            float qs = (colbase < qlimit) ? 0.125f : 1.0f;   // qlimit%4==0 -> uniform
            float v[4];
#pragma unroll
            for (int r = 0; r < 4; r++) {
                float t = (acc[mi][ni][r] + bvv[r]) * qs;
                if (act == 1) t = t / (1.0f + __expf(-t));
                v[r] = t;
            }
            if (Xres) {
                float4 x4 = *(float4*)&Xres[(size_t)row * D_EMB + colbase];
                x4.x += v[0]; x4.y += v[1]; x4.z += v[2]; x4.w += v[3];
                *(float4*)&Xres[(size_t)row * D_EMB + colbase] = x4;
            } else if (VTout && colbase >= vcol0) {
                int hc = colbase - vcol0;
                int hh = hc >> 6, ebase = hc & 63;
                int tok = row;
#pragma unroll
                for (int r = 0; r < 4; r++) {
                    int e = ebase + r;
                    int sl = ((((tok >> 3) & 7) ^ (e & 7)) << 3) | (tok & 7);
                    VTout[(size_t)(hh * 64 + e) * vtok + (tok & ~63) + sl] = (__bf16)v[r];
                }
            } else if (colbase >= kcol0 && colbase < kcol1) {
                int hc = colbase - kcol0;
                int hh = hc >> 6, ebase = hc & 63;
                int tok = row;
                int es = (((ebase >> 3) ^ (tok & 7)) << 3) | (ebase & 7);
                bf16x4 pv;
#pragma unroll
                for (int r = 0; r < 4; r++) pv[r] = (__bf16)v[r];
                *(bf16x4*)&Cb[(size_t)tok * ldc + kcol0 + hh * 64 + es] = pv;
            } else {
                __bf16* dst = Cb + (size_t)kz * PART_STRIDE;
                bf16x4 pv;
#pragma unroll
                for (int r = 0; r < 4; r++) pv[r] = (__bf16)v[r];
                *(bf16x4*)&dst[(size_t)row * ldc + colbase] = pv;
            }
        }
    }
}

// ---------------- flash MFMA attention, 128 q/block, swizzled K/V -----------
// RUNTIME strides (r13 version: compile-time KVT made the compiler unroll
// the 3-barrier tile loop -> regression). Block mapping XCD-grouped:
// bh = n%96, qt = n/96 -> the 8 q-blocks of one (b,h) share n%8 -> same XCD.
// Xin: if non-null, X[i] = Xin[i] + O (first residual); else X[i] += O.
__global__ __launch_bounds__(128, 2) void mfma_attn(
    const __bf16* __restrict__ Q, int qld,
    const __bf16* __restrict__ Kp, int kld,
    const __bf16* __restrict__ VTg, int vtok,
    int kv_tokens, float* __restrict__ X, const float* __restrict__ Xin) {
    __shared__ __bf16 Kt[64 * 64];     // [s][d] swizzled granules
    __shared__ __bf16 VT[80 * 64];     // [e][s] swizzled; rows 64..79 ones/zeros
    __shared__ __bf16 Ps[128 * 76];    // [q][s] stride 76; also Q staging (stride 64)
    int tid = threadIdx.x;
    int bh = blockIdx.x % 96;          // XCD-grouping: n%8 == bh%8
    int qt = blockIdx.x / 96;
    int b = bh / N_HEADS, h = bh - b * N_HEADS;
    int w = tid >> 6, lane = tid & 63, c = lane & 15, quad = lane >> 4;
    int q0 = qt * 128;

    for (int i = tid; i < 16 * 64; i += 128)
        VT[64 * 64 + i] = (i < 64) ? (__bf16)1.0f : (__bf16)0.0f;

    {
        const __bf16* Qg = Q + (size_t)(b * T_IMG + q0 + (tid >> 3)) * qld
                           + h * HEAD + (tid & 7) * 8;
        char* QsB = (char*)Ps + w * 1024;
#pragma unroll
        for (int j = 0; j < 8; j++)
            gld16(Qg + (size_t)j * 16 * qld, QsB + j * 2048);
    }
    __syncthreads();
    bf16x8 qa[4][2];
#pragma unroll
    for (int st = 0; st < 4; st++)
#pragma unroll
        for (int ch = 0; ch < 2; ch++)
            qa[st][ch] = *(const bf16x8*)&Ps[(w * 64 + st * 16 + c) * 64 + ch * 32 + quad * 8];
    __syncthreads();

    f32x4 o[4][5];
#pragma unroll
    for (int st = 0; st < 4; st++)
#pragma unroll
        for (int ut = 0; ut < 5; ut++) o[st][ut] = (f32x4){0.f, 0.f, 0.f, 0.f};

    char* KtB = (char*)Kt + w * 1024;
    char* VtB = (char*)VT + w * 1024;
    int ntiles = kv_tokens >> 6;
    for (int t = 0; t < ntiles; t++) {
        const __bf16* Kg = Kp + (size_t)(b * kv_tokens + t * 64 + (tid >> 3)) * kld
                           + h * HEAD + (tid & 7) * 8;
        const __bf16* Vg = VTg + (size_t)(h * HEAD + (tid >> 3)) * vtok
                           + b * kv_tokens + t * 64 + (tid & 7) * 8;
#pragma unroll
        for (int j = 0; j < 4; j++) {
            gld16(Kg + (size_t)j * 16 * kld, KtB + j * 2048);
            gld16(Vg + (size_t)j * 16 * vtok, VtB + j * 2048);
        }
        __syncthreads();   // (1) K/V tiles visible

        bf16x8 kb[4][2];
#pragma unroll
        for (int nt = 0; nt < 4; nt++)
#pragma unroll
            for (int ch = 0; ch < 2; ch++)
                kb[nt][ch] = *(const bf16x8*)&Kt[(nt * 16 + c) * 64
                                + (((ch * 4 + quad) ^ (c & 7)) << 3)];
#pragma unroll
        for (int st = 0; st < 4; st++) {
            f32x4 s[4];
#pragma unroll
            for (int nt = 0; nt < 4; nt++) {
                s[nt] = (f32x4){0.f, 0.f, 0.f, 0.f};
                s[nt] = __builtin_amdgcn_mfma_f32_16x16x32_bf16(kb[nt][0], qa[st][0], s[nt], 0, 0, 0);
                s[nt] = __builtin_amdgcn_mfma_f32_16x16x32_bf16(kb[nt][1], qa[st][1], s[nt], 0, 0, 0);
            }
#pragma unroll
            for (int nt = 0; nt < 4; nt++) {
                bf16x4 pk;
#pragma unroll
                for (int r = 0; r < 4; r++) pk[r] = (__bf16)__expf(s[nt][r]);
                *(bf16x4*)&Ps[(size_t)(w * 64 + st * 16 + c) * 76 + nt * 16 + quad * 4] = pk;
            }
        }
        __syncthreads();   // (2) P visible

        bf16x8 vb[5][2];
#pragma unroll
        for (int ut = 0; ut < 5; ut++)
#pragma unroll
            for (int ch = 0; ch < 2; ch++)
                vb[ut][ch] = *(const bf16x8*)&VT[(ut * 16 + c) * 64
                                + (((ch * 4 + quad) ^ (c & 7)) << 3)];
#pragma unroll
        for (int st = 0; st < 4; st++) {
            bf16x8 pa0 = *(const bf16x8*)&Ps[(w * 64 + st * 16 + c) * 76 + quad * 8];
            bf16x8 pa1 = *(const bf16x8*)&Ps[(w * 64 + st * 16 + c) * 76 + 32 + quad * 8];
#pragma unroll
            for (int ut = 0; ut < 5; ut++) {
                o[st][ut] = __builtin_amdgcn_mfma_f32_16x16x32_bf16(pa0, vb[ut][0], o[st][ut], 0, 0, 0);
                o[st][ut] = __builtin_amdgcn_mfma_f32_16x16x32_bf16(pa1, vb[ut][1], o[st][ut], 0, 0, 0);
            }
        }
        __syncthreads();   // (3) safe to restage K/V/P
    }

#pragma unroll
    for (int st = 0; st < 4; st++) {
        float lr[4];
#pragma unroll
        for (int r = 0; r < 4; r++) lr[r] = __shfl(o[st][4][r], lane & 48, 64);
#pragma unroll
        for (int ut = 0; ut < 4; ut++) {
#pragma unroll
            for (int r = 0; r < 4; r++) {
                int row = b * T_IMG + q0 + w * 64 + st * 16 + quad * 4 + r;
                int col = h * HEAD + ut * 16 + c;
                size_t idx = (size_t)row * D_EMB + col;
                float base = Xin ? Xin[idx] : X[idx];
                X[idx] = base + o[st][ut][r] / lr[r];
            }
        }
    }
}

// ---------------------------------------------------------------------------
extern "C" void kernel_launch(void* const* d_in, const int* in_sizes, int n_in,
                              void* d_out, int out_size, void* d_ws, size_t ws_size,
                              hipStream_t stream) {
    const float* img  = (const float*)d_in[0];
    const float* ctx  = (const float*)d_in[1];
    const float* ln1w = (const float*)d_in[2];  const float* ln1b = (const float*)d_in[3];
    const float* sWq  = (const float*)d_in[4];  const float* sbq  = (const float*)d_in[5];
    const float* sWk  = (const float*)d_in[6];  const float* sbk  = (const float*)d_in[7];
    const float* sWv  = (const float*)d_in[8];  const float* sbv  = (const float*)d_in[9];
    const float* ln2w = (const float*)d_in[10]; const float* ln2b = (const float*)d_in[11];
    const float* cWq  = (const float*)d_in[12]; const float* cbq  = (const float*)d_in[13];
    const float* cWk  = (const float*)d_in[14]; const float* cbk  = (const float*)d_in[15];
    const float* cWv  = (const float*)d_in[16]; const float* cbv  = (const float*)d_in[17];
    const float* ln3w = (const float*)d_in[18]; const float* ln3b = (const float*)d_in[19];
    const float* W1   = (const float*)d_in[20]; const float* b1   = (const float*)d_in[21];
    const float* W2   = (const float*)d_in[22]; const float* b2   = (const float*)d_in[23];

    float* X = (float*)d_out;

    char* p = (char*)d_ws;
    __bf16* LNb  = (__bf16*)p; p += (size_t)ROWS_IMG * D_EMB * 2;       // 12.6 MB
    __bf16* VTg  = (__bf16*)p; p += (size_t)12 * 64 * ROWS_IMG * 2;     // 12.6 MB
    __bf16* BIG  = (__bf16*)p; p += (size_t)ROWS_IMG * FF_DIM * 2;      // 50.3 MB
    __bf16* ctxb = (__bf16*)p; p += (size_t)ROWS_CTX * D_EMB * 2;       // 3.1 MB
    __bf16* Wt   = (__bf16*)p; p += (size_t)2304 * 768 * 2;             // 3.5 MB
    __bf16* cWt  = (__bf16*)p; p += (size_t)2304 * 768 * 2;             // 3.5 MB
    __bf16* W1t  = (__bf16*)p; p += (size_t)FF_DIM * 768 * 2;           // 4.7 MB
    __bf16* W2t  = (__bf16*)p; p += (size_t)768 * FF_DIM * 2;           // 4.7 MB
    __bf16* VTc  = (__bf16*)p; p += (size_t)12 * 64 * ROWS_CTX * 2;     // 3.1 MB
    float*  bp   = (float*)p;  p += 2304 * 4;
    float*  cbp  = (float*)p;  p += 2304 * 4;
    __bf16* Pk   = LNb;   // split-K partials overlay (LNb+VTg dead by stage 3)
    __bf16* QKVb = BIG;
    __bf16* Qc   = BIG;
    __bf16* KVc  = BIG + (size_t)ROWS_IMG * 768;
    __bf16* FFh  = BIG;

    // ---- weight preprocessing (no copy4: attn1 fuses X = img + O) ----
    cvt_bf16_kernel<<<(ROWS_CTX * D_EMB / 4 + 255) / 256, 256, 0, stream>>>(
        ctx, ctxb, ROWS_CTX * D_EMB / 4);
    repack_qkv_t_kernel<<<dim3(12, 36), 256, 0, stream>>>(
        sWq, sWk, sWv, sbq, sbk, sbv, Wt, bp);
    repack_qkv_t_kernel<<<dim3(12, 36), 256, 0, stream>>>(
        cWq, cWk, cWv, cbq, cbk, cbv, cWt, cbp);
    transpose_cvt_kernel<<<dim3(FF_DIM / 64, 768 / 64), 256, 0, stream>>>(
        W1, W1t, 768, FF_DIM);
    transpose_cvt_kernel<<<dim3(768 / 64, FF_DIM / 64), 256, 0, stream>>>(
        W2, W2t, FF_DIM, 768);

    // ---- stage 1: self attention (ln1 reads img directly) ----
    ln_kernel<<<ROWS_IMG, 256, 0, stream>>>(img, ln1w, ln1b, LNb);
    mfma_gemm_bt<768, 768><<<dim3(2304 / 128, ROWS_IMG / 128), 256, 0, stream>>>(
        LNb, Wt, bp, QKVb, 2304, D_EMB, 0, 768,
        VTg, ROWS_IMG, 1536, 768, 1536, nullptr);
    mfma_attn<<<96 * 8, 128, 0, stream>>>(
        QKVb, 2304, QKVb + 768, 2304, VTg, ROWS_IMG, T_IMG, X, img);

    // ---- stage 2: cross attention ----
    ln_kernel<<<ROWS_IMG, 256, 0, stream>>>(X, ln2w, ln2b, LNb);
    mfma_gemm_bt<768, 768><<<dim3(768 / 128, ROWS_IMG / 128), 256, 0, stream>>>(
        LNb, cWt, cbp, Qc, 768, D_EMB, 0, 768,
        nullptr, 0, BIGCOL, BIGCOL, BIGCOL, nullptr);
    mfma_gemm_bt<768, 768><<<dim3(1536 / 128, ROWS_CTX / 128), 256, 0, stream>>>(
        ctxb, cWt + (size_t)768 * 768, cbp + 768,
        KVc, 1536, D_EMB, 0, 0,
        VTc, ROWS_CTX, 768, 0, 768, nullptr);
    mfma_attn<<<96 * 8, 128, 0, stream>>>(
        Qc, 768, KVc, 1536, VTc, ROWS_CTX, T_CTX, X, nullptr);

    // ---- stage 3: MLP (W1 single pass; W2 split-K x2 + fused reduce) ----
    ln_kernel<<<ROWS_IMG, 256, 0, stream>>>(X, ln3w, ln3b, LNb);
    mfma_gemm_bt<768, 768><<<dim3(FF_DIM / 128, ROWS_IMG / 128), 256, 0, stream>>>(
        LNb, W1t, b1, FFh, FF_DIM, D_EMB, 1, 0,
        nullptr, 0, BIGCOL, BIGCOL, BIGCOL, nullptr);
    mfma_gemm_bt<3072, 3072><<<dim3(768 / 128, ROWS_IMG / 128, 2), 256, 0, stream>>>(
        FFh, W2t, nullptr, Pk, D_EMB, 1536, 0, 0,
        nullptr, 0, BIGCOL, BIGCOL, BIGCOL, nullptr);
    reduce_w2_kernel<<<ROWS_IMG * D_EMB / 4 / 256, 256, 0, stream>>>(Pk, b2, X);
}

// Round 10
// 475.484 us; speedup vs baseline: 1.0124x; 1.0124x over previous
//
#include <hip/hip_runtime.h>
#include <hip/hip_bf16.h>

// ---------------------------------------------------------------------------
// DiT block, bf16 MFMA, round 17.
// vs r16: dispatch-count reduction (16 -> 11). (1) All 5 preprocessing
// kernels (ctx cvt, 2x qkv repack, 2x weight transpose) merged into ONE
// block-range-decoded preproc_kernel. (2) Qc + KVc cross-attn GEMMs merged
// into ONE 576-block dispatch (each was badly under-filled: 1.5 and 0.75
// blocks/CU serially; merged they co-run at 2.25/CU). GEMM body refactored
// into a __forceinline__ device fn shared by the main wrapper (identical
// codegen path) and the merged kernel. Hot loops byte-identical to r16.
// ---------------------------------------------------------------------------

#define D_EMB 768
#define N_HEADS 12
#define HEAD 64
#define B_SZ 8
#define T_IMG 1024
#define T_CTX 256
#define FF_DIM 3072
#define ROWS_IMG (B_SZ * T_IMG)      // 8192
#define ROWS_CTX (B_SZ * T_CTX)     // 2048
#define BIGCOL (1 << 28)
#define PART_STRIDE (ROWS_IMG * D_EMB)   // split-K partial stride (elems)

typedef __bf16 bf16x8 __attribute__((ext_vector_type(8)));
typedef __bf16 bf16x4 __attribute__((ext_vector_type(4)));
typedef float f32x4 __attribute__((ext_vector_type(4)));

__device__ __forceinline__ void gld16(const void* g, void* l) {
    __builtin_amdgcn_global_load_lds(
        (const __attribute__((address_space(1))) unsigned int*)g,
        (__attribute__((address_space(3))) unsigned int*)l, 16, 0, 0);
}

// ---------------- W2 split-K reduce: X += P0 + P1 + b2 ----------------
__global__ __launch_bounds__(256) void reduce_w2_kernel(
    const __bf16* __restrict__ P, const float* __restrict__ b2,
    float* __restrict__ X) {
    int i = blockIdx.x * 256 + threadIdx.x;
    int base = i * 4;
    int col = base % D_EMB;
    bf16x4 p0 = *(const bf16x4*)&P[base];
    bf16x4 p1 = *(const bf16x4*)&P[PART_STRIDE + base];
    float4 x = *(float4*)&X[base];
    float4 bb = *(const float4*)&b2[col];
    x.x += (float)p0[0] + (float)p1[0] + bb.x;
    x.y += (float)p0[1] + (float)p1[1] + bb.y;
    x.z += (float)p0[2] + (float)p1[2] + bb.z;
    x.w += (float)p0[3] + (float)p1[3] + bb.w;
    *(float4*)&X[base] = x;
}

// ---------------- preproc device bodies (verified code, re-routed) ---------
__device__ __forceinline__ void transpose_cvt_body(
    float (*tile)[65], const float* __restrict__ src, __bf16* __restrict__ dst,
    int src_rows, int src_cols, int bx, int by, int tid) {
    int r0 = by * 64, c0 = bx * 64;
    int lr = tid >> 4, lc = (tid & 15) * 4;
#pragma unroll
    for (int i = 0; i < 4; i++) {
        float4 v = *(const float4*)&src[(size_t)(r0 + i * 16 + lr) * src_cols + c0 + lc];
        tile[i * 16 + lr][lc] = v.x; tile[i * 16 + lr][lc + 1] = v.y;
        tile[i * 16 + lr][lc + 2] = v.z; tile[i * 16 + lr][lc + 3] = v.w;
    }
    __syncthreads();
#pragma unroll
    for (int i = 0; i < 4; i++) {
        int cc = i * 16 + lr;
        int rr = (tid & 15) * 4;
        bf16x4 o;
#pragma unroll
        for (int j = 0; j < 4; j++) o[j] = (__bf16)tile[rr + j][cc];
        *(bf16x4*)&dst[(size_t)(c0 + cc) * src_rows + r0 + rr] = o;
    }
}

__device__ __forceinline__ void repack_body(
    float (*tile)[65],
    const float* __restrict__ Wq, const float* __restrict__ Wk,
    const float* __restrict__ Wv, const float* __restrict__ bq,
    const float* __restrict__ bk, const float* __restrict__ bv,
    __bf16* __restrict__ Wt, float* __restrict__ bp, int bx, int byy, int tid) {
    int which = byy / 12, h = byy - which * 12;
    int d0 = bx * 64;
    const float* W = (which == 0) ? Wq : ((which == 1) ? Wk : Wv);
    const float* src = W + ((size_t)h * D_EMB + d0) * HEAD;
    int lr = tid >> 4, lc = (tid & 15) * 4;
#pragma unroll
    for (int i = 0; i < 4; i++) {
        float4 v = *(const float4*)&src[(size_t)(i * 16 + lr) * HEAD + lc];
        tile[i * 16 + lr][lc] = v.x; tile[i * 16 + lr][lc + 1] = v.y;
        tile[i * 16 + lr][lc + 2] = v.z; tile[i * 16 + lr][lc + 3] = v.w;
    }
    __syncthreads();
#pragma unroll
    for (int i = 0; i < 4; i++) {
        int e = i * 16 + lr;
        int dd = (tid & 15) * 4;
        bf16x4 o;
#pragma unroll
        for (int j = 0; j < 4; j++) o[j] = (__bf16)tile[dd + j][e];
        *(bf16x4*)&Wt[(size_t)(which * 768 + h * 64 + e) * D_EMB + d0 + dd] = o;
    }
    if (bx == 0 && tid < 64) {
        const float* bb = (which == 0) ? bq : ((which == 1) ? bk : bv);
        bp[which * 768 + h * 64 + tid] = bb[h * 64 + tid];
    }
}

// ---------------- merged preprocessing: 1 dispatch, block-range decode -----
// [0,1536): ctx fp32->bf16 | [1536,1968): repack self | [1968,2400): repack
// cross | [2400,2976): transpose W1 (48x12) | [2976,3552): transpose W2 (12x48)
__global__ __launch_bounds__(256) void preproc_kernel(
    const float* __restrict__ ctx, __bf16* __restrict__ ctxb,
    const float* __restrict__ sWq, const float* __restrict__ sWk,
    const float* __restrict__ sWv, const float* __restrict__ sbq,
    const float* __restrict__ sbk, const float* __restrict__ sbv,
    __bf16* __restrict__ Wt, float* __restrict__ bp,
    const float* __restrict__ cWq, const float* __restrict__ cWk,
    const float* __restrict__ cWv, const float* __restrict__ cbq,
    const float* __restrict__ cbk, const float* __restrict__ cbv,
    __bf16* __restrict__ cWt, float* __restrict__ cbp,
    const float* __restrict__ W1, __bf16* __restrict__ W1t,
    const float* __restrict__ W2, __bf16* __restrict__ W2t) {
    __shared__ float tile[64][65];
    int bid = blockIdx.x;
    int tid = threadIdx.x;
    if (bid < 1536) {
        int i = bid * 256 + tid;                 // n4 = 393216, exact
        float4 v = ((const float4*)ctx)[i];
        __bf16* d = ctxb + i * 4;
        d[0] = (__bf16)v.x; d[1] = (__bf16)v.y; d[2] = (__bf16)v.z; d[3] = (__bf16)v.w;
    } else if (bid < 1968) {
        int vb = bid - 1536;
        repack_body(tile, sWq, sWk, sWv, sbq, sbk, sbv, Wt, bp,
                    vb % 12, vb / 12, tid);
    } else if (bid < 2400) {
        int vb = bid - 1968;
        repack_body(tile, cWq, cWk, cWv, cbq, cbk, cbv, cWt, cbp,
                    vb % 12, vb / 12, tid);
    } else if (bid < 2976) {
        int vb = bid - 2400;
        transpose_cvt_body(tile, W1, W1t, 768, FF_DIM, vb % 48, vb / 48, tid);
    } else {
        int vb = bid - 2976;
        transpose_cvt_body(tile, W2, W2t, FF_DIM, 768, vb % 12, vb / 12, tid);
    }
}

// ---------------- layernorm over 768, bf16 output ----------------
__global__ __launch_bounds__(256) void ln_kernel(const float* __restrict__ x,
                                                 const float* __restrict__ lw,
                                                 const float* __restrict__ lb,
                                                 __bf16* __restrict__ y) {
    int row = blockIdx.x;
    int tid = threadIdx.x;
    const float* xr = x + (size_t)row * D_EMB;
    float a0 = xr[tid], a1 = xr[tid + 256], a2 = xr[tid + 512];
    float s = a0 + a1 + a2;
    float ss = a0 * a0 + a1 * a1 + a2 * a2;
#pragma unroll
    for (int off = 32; off > 0; off >>= 1) {
        s += __shfl_down(s, off, 64);
        ss += __shfl_down(ss, off, 64);
    }
    __shared__ float red[8];
    __shared__ float stats[2];
    int wv = tid >> 6, lane = tid & 63;
    if (lane == 0) { red[wv] = s; red[4 + wv] = ss; }
    __syncthreads();
    if (tid == 0) {
        float S = red[0] + red[1] + red[2] + red[3];
        float SS = red[4] + red[5] + red[6] + red[7];
        float mu = S * (1.0f / D_EMB);
        float var = SS * (1.0f / D_EMB) - mu * mu;
        stats[0] = mu;
        stats[1] = rsqrtf(var + 1e-5f);
    }
    __syncthreads();
    float mu = stats[0], rs = stats[1];
    __bf16* yr = y + (size_t)row * D_EMB;
    yr[tid]       = (__bf16)((a0 - mu) * rs * lw[tid]       + lb[tid]);
    yr[tid + 256] = (__bf16)((a1 - mu) * rs * lw[tid + 256] + lb[tid + 256]);
    yr[tid + 512] = (__bf16)((a2 - mu) * rs * lw[tid + 512] + lb[tid + 512]);
}

// ---------------- bf16 MFMA GEMM body (B^T layout), swapped operands -------
// BK=64, XOR-swizzled LDS (zero bank conflicts), compile-time LDA/LDB.
__device__ __forceinline__ bf16x8 lds_frag(const __bf16* h, int row, int kk, int quad) {
    int off = (kk * 32 + quad * 8) ^ ((row & 7) << 3);    // swizzled read
    return *(const bf16x8*)&h[row * 64 + off];
}

template <int LDA, int LDB>
__device__ __forceinline__ void gemm_body(
    int bx, int by, int kz, int tid,
    const __bf16* __restrict__ A,
    const __bf16* __restrict__ Bt,
    const float* __restrict__ bias,
    __bf16* __restrict__ Cb, int ldc,
    int Kc, int act, int qlimit,
    __bf16* __restrict__ VTout, int vtok, int vcol0, int kcol0, int kcol1,
    float* __restrict__ Xres,
    __bf16* As, __bf16* Bs) {
    int w = tid >> 6, lane = tid & 63;
    int c = lane & 15, quad = lane >> 4;
    int wm = (w >> 1) * 64, wn = (w & 1) * 64;

    f32x4 acc[4][4];
#pragma unroll
    for (int i = 0; i < 4; i++)
#pragma unroll
        for (int j = 0; j < 4; j++) acc[i][j] = (f32x4){0.f, 0.f, 0.f, 0.f};

    // staging: 256 threads x 4 x 16B per operand tile (128 rows x 64 cols).
    // source col pre-swizzled with the row-XOR so linear LDS + swizzled read
    // = identity (verified r8-r16, 0 conflicts).
    int srow = tid >> 3;                                   // 0..31
    int scol = ((tid & 7) * 8) ^ ((srow & 7) * 8);         // inverse swizzle
    const __bf16* Ag = A + (size_t)(by * 128 + srow) * LDA + (size_t)kz * Kc + scol;
    const __bf16* Bg = Bt + (size_t)(bx * 128 + srow) * LDB + (size_t)kz * Kc + scol;
    char* AsB = (char*)As + w * 1024;
    char* BsB = (char*)Bs + w * 1024;

    for (int k0 = 0; k0 < Kc; k0 += 64) {
#pragma unroll
        for (int j = 0; j < 4; j++) {
            gld16(Ag + (size_t)(j * 32) * LDA + k0, AsB + j * 4096);
            gld16(Bg + (size_t)(j * 32) * LDB + k0, BsB + j * 4096);
        }
        __syncthreads();
#pragma unroll
        for (int kk = 0; kk < 2; kk++) {
            bf16x8 af[4], bfr[4];
#pragma unroll
            for (int mi = 0; mi < 4; mi++)
                af[mi] = lds_frag(As, wm + mi * 16 + c, kk, quad);
#pragma unroll
            for (int ni = 0; ni < 4; ni++)
                bfr[ni] = lds_frag(Bs, wn + ni * 16 + c, kk, quad);
#pragma unroll
            for (int mi = 0; mi < 4; mi++)
#pragma unroll
                for (int ni = 0; ni < 4; ni++)
                    acc[mi][ni] = __builtin_amdgcn_mfma_f32_16x16x32_bf16(
                        bfr[ni], af[mi], acc[mi][ni], 0, 0, 0);   // swapped: C^T
        }
        __syncthreads();
    }

#pragma unroll
    for (int mi = 0; mi < 4; mi++) {
#pragma unroll
        for (int ni = 0; ni < 4; ni++) {
            int row = by * 128 + wm + mi * 16 + c;                 // C row
            int colbase = bx * 128 + wn + ni * 16 + quad * 4;      // 4 consecutive C cols
            float bvv[4] = {0.f, 0.f, 0.f, 0.f};
            if (bias && kz == 0) {
                float4 b4 = *(const float4*)&bias[colbase];
                bvv[0] = b4.x; bvv[1] = b4.y; bvv[2] = b4.z; bvv[3] = b4.w;
            }
            float qs = (colbase < qlimit) ? 0.125f : 1.0f;   // qlimit%4==0 -> uniform
            float v[4];
#pragma unroll
            for (int r = 0; r < 4; r++) {
                float t = (acc[mi][ni][r] + bvv[r]) * qs;
                if (act == 1) t = t / (1.0f + __expf(-t));
                v[r] = t;
            }
            if (Xres) {
                float4 x4 = *(float4*)&Xres[(size_t)row * D_EMB + colbase];
                x4.x += v[0]; x4.y += v[1]; x4.z += v[2]; x4.w += v[3];
                *(float4*)&Xres[(size_t)row * D_EMB + colbase] = x4;
            } else if (VTout && colbase >= vcol0) {
                int hc = colbase - vcol0;
                int hh = hc >> 6, ebase = hc & 63;
                int tok = row;
#pragma unroll
                for (int r = 0; r < 4; r++) {
                    int e = ebase + r;
                    int sl = ((((tok >> 3) & 7) ^ (e & 7)) << 3) | (tok & 7);
                    VTout[(size_t)(hh * 64 + e) * vtok + (tok & ~63) + sl] = (__bf16)v[r];
                }
            } else if (colbase >= kcol0 && colbase < kcol1) {
                int hc = colbase - kcol0;
                int hh = hc >> 6, ebase = hc & 63;
                int tok = row;
                int es = (((ebase >> 3) ^ (tok & 7)) << 3) | (ebase & 7);
                bf16x4 pv;
#pragma unroll
                for (int r = 0; r < 4; r++) pv[r] = (__bf16)v[r];
                *(bf16x4*)&Cb[(size_t)tok * ldc + kcol0 + hh * 64 + es] = pv;
            } else {
                __bf16* dst = Cb + (size_t)kz * PART_STRIDE;
                bf16x4 pv;
#pragma unroll
                for (int r = 0; r < 4; r++) pv[r] = (__bf16)v[r];
                *(bf16x4*)&dst[(size_t)row * ldc + colbase] = pv;
            }
        }
    }
}

template <int LDA, int LDB>
__global__ __launch_bounds__(256) void mfma_gemm_bt(
    const __bf16* __restrict__ A,
    const __bf16* __restrict__ Bt,
    const float* __restrict__ bias,
    __bf16* __restrict__ Cb, int ldc,
    int Kc, int act, int qlimit,
    __bf16* __restrict__ VTout, int vtok, int vcol0, int kcol0, int kcol1,
    float* __restrict__ Xres) {
    __shared__ __bf16 As[128 * 64];   // 16 KiB
    __shared__ __bf16 Bs[128 * 64];   // 16 KiB
    // bijective XCD grouping swizzle (requires nwg%8==0; true for all grids)
    int gx = gridDim.x;
    int nwg = gx * gridDim.y;
    int orig = blockIdx.y * gx + blockIdx.x;
    int swz = (orig & 7) * (nwg >> 3) + (orig >> 3);
    gemm_body<LDA, LDB>(swz % gx, swz / gx, blockIdx.z, threadIdx.x,
                        A, Bt, bias, Cb, ldc, Kc, act, qlimit,
                        VTout, vtok, vcol0, kcol0, kcol1, Xres, As, Bs);
}

// ---------------- merged cross-attn GEMMs: Qc (384 blks) + KVc (192 blks) --
__global__ __launch_bounds__(256) void cross_gemm_kernel(
    const __bf16* __restrict__ LNb, const __bf16* __restrict__ cWt,
    const float* __restrict__ cbp, const __bf16* __restrict__ ctxb,
    __bf16* __restrict__ Qc, __bf16* __restrict__ KVc,
    __bf16* __restrict__ VTc) {
    __shared__ __bf16 As[128 * 64];
    __shared__ __bf16 Bs[128 * 64];
    int bid = blockIdx.x;
    if (bid < 384) {
        // Qc: M=8192 N=768 K=768, grid 6x64, XCD swizzle within range
        int swz = (bid & 7) * 48 + (bid >> 3);
        gemm_body<768, 768>(swz % 6, swz / 6, 0, threadIdx.x,
                            LNb, cWt, cbp, Qc, 768, D_EMB, 0, 768,
                            nullptr, 0, BIGCOL, BIGCOL, BIGCOL, nullptr, As, Bs);
    } else {
        // KVc: M=2048 N=1536 K=768, grid 12x16 ((bid-384)%8 == bid%8, 384%8==0)
        int b2 = bid - 384;
        int swz = (b2 & 7) * 24 + (b2 >> 3);
        gemm_body<768, 768>(swz % 12, swz / 12, 0, threadIdx.x,
                            ctxb, cWt + (size_t)768 * 768, cbp + 768,
                            KVc, 1536, D_EMB, 0, 0,
                            VTc, ROWS_CTX, 768, 0, 768, nullptr, As, Bs);
    }
}

// ---------------- flash MFMA attention, 128 q/block, swizzled K/V -----------
// RUNTIME strides (compile-time KVT unrolled the 3-barrier loop -> regression).
// Block mapping XCD-grouped: bh = n%96, qt = n/96. Xin: if non-null,
// X[i] = Xin[i] + O (first residual); else X[i] += O.
__global__ __launch_bounds__(128, 2) void mfma_attn(
    const __bf16* __restrict__ Q, int qld,
    const __bf16* __restrict__ Kp, int kld,
    const __bf16* __restrict__ VTg, int vtok,
    int kv_tokens, float* __restrict__ X, const float* __restrict__ Xin) {
    __shared__ __bf16 Kt[64 * 64];     // [s][d] swizzled granules
    __shared__ __bf16 VT[80 * 64];     // [e][s] swizzled; rows 64..79 ones/zeros
    __shared__ __bf16 Ps[128 * 76];    // [q][s] stride 76; also Q staging (stride 64)
    int tid = threadIdx.x;
    int bh = blockIdx.x % 96;          // XCD-grouping: n%8 == bh%8
    int qt = blockIdx.x / 96;
    int b = bh / N_HEADS, h = bh - b * N_HEADS;
    int w = tid >> 6, lane = tid & 63, c = lane & 15, quad = lane >> 4;
    int q0 = qt * 128;

    for (int i = tid; i < 16 * 64; i += 128)
        VT[64 * 64 + i] = (i < 64) ? (__bf16)1.0f : (__bf16)0.0f;

    {
        const __bf16* Qg = Q + (size_t)(b * T_IMG + q0 + (tid >> 3)) * qld
                           + h * HEAD + (tid & 7) * 8;
        char* QsB = (char*)Ps + w * 1024;
#pragma unroll
        for (int j = 0; j < 8; j++)
            gld16(Qg + (size_t)j * 16 * qld, QsB + j * 2048);
    }
    __syncthreads();
    bf16x8 qa[4][2];
#pragma unroll
    for (int st = 0; st < 4; st++)
#pragma unroll
        for (int ch = 0; ch < 2; ch++)
            qa[st][ch] = *(const bf16x8*)&Ps[(w * 64 + st * 16 + c) * 64 + ch * 32 + quad * 8];
    __syncthreads();

    f32x4 o[4][5];
#pragma unroll
    for (int st = 0; st < 4; st++)
#pragma unroll
        for (int ut = 0; ut < 5; ut++) o[st][ut] = (f32x4){0.f, 0.f, 0.f, 0.f};

    char* KtB = (char*)Kt + w * 1024;
    char* VtB = (char*)VT + w * 1024;
    int ntiles = kv_tokens >> 6;
    for (int t = 0; t < ntiles; t++) {
        const __bf16* Kg = Kp + (size_t)(b * kv_tokens + t * 64 + (tid >> 3)) * kld
                           + h * HEAD + (tid & 7) * 8;
        const __bf16* Vg = VTg + (size_t)(h * HEAD + (tid >> 3)) * vtok
                           + b * kv_tokens + t * 64 + (tid & 7) * 8;
#pragma unroll
        for (int j = 0; j < 4; j++) {
            gld16(Kg + (size_t)j * 16 * kld, KtB + j * 2048);
            gld16(Vg + (size_t)j * 16 * vtok, VtB + j * 2048);
        }
        __syncthreads();   // (1) K/V tiles visible

        bf16x8 kb[4][2];
#pragma unroll
        for (int nt = 0; nt < 4; nt++)
#pragma unroll
            for (int ch = 0; ch < 2; ch++)
                kb[nt][ch] = *(const bf16x8*)&Kt[(nt * 16 + c) * 64
                                + (((ch * 4 + quad) ^ (c & 7)) << 3)];
#pragma unroll
        for (int st = 0; st < 4; st++) {
            f32x4 s[4];
#pragma unroll
            for (int nt = 0; nt < 4; nt++) {
                s[nt] = (f32x4){0.f, 0.f, 0.f, 0.f};
                s[nt] = __builtin_amdgcn_mfma_f32_16x16x32_bf16(kb[nt][0], qa[st][0], s[nt], 0, 0, 0);
                s[nt] = __builtin_amdgcn_mfma_f32_16x16x32_bf16(kb[nt][1], qa[st][1], s[nt], 0, 0, 0);
            }
#pragma unroll
            for (int nt = 0; nt < 4; nt++) {
                bf16x4 pk;
#pragma unroll
                for (int r = 0; r < 4; r++) pk[r] = (__bf16)__expf(s[nt][r]);
                *(bf16x4*)&Ps[(size_t)(w * 64 + st * 16 + c) * 76 + nt * 16 + quad * 4] = pk;
            }
        }
        __syncthreads();   // (2) P visible

        bf16x8 vb[5][2];
#pragma unroll
        for (int ut = 0; ut < 5; ut++)
#pragma unroll
            for (int ch = 0; ch < 2; ch++)
                vb[ut][ch] = *(const bf16x8*)&VT[(ut * 16 + c) * 64
                                + (((ch * 4 + quad) ^ (c & 7)) << 3)];
#pragma unroll
        for (int st = 0; st < 4; st++) {
            bf16x8 pa0 = *(const bf16x8*)&Ps[(w * 64 + st * 16 + c) * 76 + quad * 8];
            bf16x8 pa1 = *(const bf16x8*)&Ps[(w * 64 + st * 16 + c) * 76 + 32 + quad * 8];
#pragma unroll
            for (int ut = 0; ut < 5; ut++) {
                o[st][ut] = __builtin_amdgcn_mfma_f32_16x16x32_bf16(pa0, vb[ut][0], o[st][ut], 0, 0, 0);
                o[st][ut] = __builtin_amdgcn_mfma_f32_16x16x32_bf16(pa1, vb[ut][1], o[st][ut], 0, 0, 0);
            }
        }
        __syncthreads();   // (3) safe to restage K/V/P
    }

#pragma unroll
    for (int st = 0; st < 4; st++) {
        float lr[4];
#pragma unroll
        for (int r = 0; r < 4; r++) lr[r] = __shfl(o[st][4][r], lane & 48, 64);
#pragma unroll
        for (int ut = 0; ut < 4; ut++) {
#pragma unroll
            for (int r = 0; r < 4; r++) {
                int row = b * T_IMG + q0 + w * 64 + st * 16 + quad * 4 + r;
                int col = h * HEAD + ut * 16 + c;
                size_t idx = (size_t)row * D_EMB + col;
                float base = Xin ? Xin[idx] : X[idx];
                X[idx] = base + o[st][ut][r] / lr[r];
            }
        }
    }
}

// ---------------------------------------------------------------------------
extern "C" void kernel_launch(void* const* d_in, const int* in_sizes, int n_in,
                              void* d_out, int out_size, void* d_ws, size_t ws_size,
                              hipStream_t stream) {
    const float* img  = (const float*)d_in[0];
    const float* ctx  = (const float*)d_in[1];
    const float* ln1w = (const float*)d_in[2];  const float* ln1b = (const float*)d_in[3];
    const float* sWq  = (const float*)d_in[4];  const float* sbq  = (const float*)d_in[5];
    const float* sWk  = (const float*)d_in[6];  const float* sbk  = (const float*)d_in[7];
    const float* sWv  = (const float*)d_in[8];  const float* sbv  = (const float*)d_in[9];
    const float* ln2w = (const float*)d_in[10]; const float* ln2b = (const float*)d_in[11];
    const float* cWq  = (const float*)d_in[12]; const float* cbq  = (const float*)d_in[13];
    const float* cWk  = (const float*)d_in[14]; const float* cbk  = (const float*)d_in[15];
    const float* cWv  = (const float*)d_in[16]; const float* cbv  = (const float*)d_in[17];
    const float* ln3w = (const float*)d_in[18]; const float* ln3b = (const float*)d_in[19];
    const float* W1   = (const float*)d_in[20]; const float* b1   = (const float*)d_in[21];
    const float* W2   = (const float*)d_in[22]; const float* b2   = (const float*)d_in[23];

    float* X = (float*)d_out;

    char* p = (char*)d_ws;
    __bf16* LNb  = (__bf16*)p; p += (size_t)ROWS_IMG * D_EMB * 2;       // 12.6 MB
    __bf16* VTg  = (__bf16*)p; p += (size_t)12 * 64 * ROWS_IMG * 2;     // 12.6 MB
    __bf16* BIG  = (__bf16*)p; p += (size_t)ROWS_IMG * FF_DIM * 2;      // 50.3 MB
    __bf16* ctxb = (__bf16*)p; p += (size_t)ROWS_CTX * D_EMB * 2;       // 3.1 MB
    __bf16* Wt   = (__bf16*)p; p += (size_t)2304 * 768 * 2;             // 3.5 MB
    __bf16* cWt  = (__bf16*)p; p += (size_t)2304 * 768 * 2;             // 3.5 MB
    __bf16* W1t  = (__bf16*)p; p += (size_t)FF_DIM * 768 * 2;           // 4.7 MB
    __bf16* W2t  = (__bf16*)p; p += (size_t)768 * FF_DIM * 2;           // 4.7 MB
    __bf16* VTc  = (__bf16*)p; p += (size_t)12 * 64 * ROWS_CTX * 2;     // 3.1 MB
    float*  bp   = (float*)p;  p += 2304 * 4;
    float*  cbp  = (float*)p;  p += 2304 * 4;
    __bf16* Pk   = LNb;   // split-K partials overlay (LNb+VTg dead by stage 3)
    __bf16* QKVb = BIG;
    __bf16* Qc   = BIG;
    __bf16* KVc  = BIG + (size_t)ROWS_IMG * 768;
    __bf16* FFh  = BIG;

    // ---- all preprocessing in ONE dispatch ----
    preproc_kernel<<<3552, 256, 0, stream>>>(
        ctx, ctxb,
        sWq, sWk, sWv, sbq, sbk, sbv, Wt, bp,
        cWq, cWk, cWv, cbq, cbk, cbv, cWt, cbp,
        W1, W1t, W2, W2t);

    // ---- stage 1: self attention (ln1 reads img; attn1 fuses X = img + O) --
    ln_kernel<<<ROWS_IMG, 256, 0, stream>>>(img, ln1w, ln1b, LNb);
    mfma_gemm_bt<768, 768><<<dim3(2304 / 128, ROWS_IMG / 128), 256, 0, stream>>>(
        LNb, Wt, bp, QKVb, 2304, D_EMB, 0, 768,
        VTg, ROWS_IMG, 1536, 768, 1536, nullptr);
    mfma_attn<<<96 * 8, 128, 0, stream>>>(
        QKVb, 2304, QKVb + 768, 2304, VTg, ROWS_IMG, T_IMG, X, img);

    // ---- stage 2: cross attention (Qc + KVc in ONE dispatch) ----
    ln_kernel<<<ROWS_IMG, 256, 0, stream>>>(X, ln2w, ln2b, LNb);
    cross_gemm_kernel<<<576, 256, 0, stream>>>(LNb, cWt, cbp, ctxb, Qc, KVc, VTc);
    mfma_attn<<<96 * 8, 128, 0, stream>>>(
        Qc, 768, KVc, 1536, VTc, ROWS_CTX, T_CTX, X, nullptr);

    // ---- stage 3: MLP (W1 single pass; W2 split-K x2 + fused reduce) ----
    ln_kernel<<<ROWS_IMG, 256, 0, stream>>>(X, ln3w, ln3b, LNb);
    mfma_gemm_bt<768, 768><<<dim3(FF_DIM / 128, ROWS_IMG / 128), 256, 0, stream>>>(
        LNb, W1t, b1, FFh, FF_DIM, D_EMB, 1, 0,
        nullptr, 0, BIGCOL, BIGCOL, BIGCOL, nullptr);
    mfma_gemm_bt<3072, 3072><<<dim3(768 / 128, ROWS_IMG / 128, 2), 256, 0, stream>>>(
        FFh, W2t, nullptr, Pk, D_EMB, 1536, 0, 0,
        nullptr, 0, BIGCOL, BIGCOL, BIGCOL, nullptr);
    reduce_w2_kernel<<<ROWS_IMG * D_EMB / 4 / 256, 256, 0, stream>>>(Pk, b2, X);
}

// Round 12
// 458.555 us; speedup vs baseline: 1.0498x; 1.0369x over previous
//
#include <hip/hip_runtime.h>
#include <hip/hip_bf16.h>

// ---------------------------------------------------------------------------
// DiT block, bf16 MFMA, round 18 (resubmit; r18 bench was an infra failure).
// vs r17: (1) attention restructured per T14 async-STAGE split: K/V tiles
// reg-staged (same addresses as the old global_load_lds path), ds_write after
// barrier(A), NEXT tile's loads issued right after barrier(B) -> full
// QK^T+softmax+PV phase of latency cover (was zero). (2) barrier "P visible"
// DELETED: P rows are written and read by the SAME wave only (w*64 offset) ->
// pure same-wave lgkm dependency, compiler-ordered; cross-wave Q-staging
// overlap is ordered by the (A)/(B) barrier pair. 3 -> 2 barriers/tile.
// (3) ln1 merged into preproc (depends only on inputs). 10 dispatches.
// GEMMs unchanged from r17 (structure ceiling: 4 failed reschedules).
// ---------------------------------------------------------------------------

#define D_EMB 768
#define N_HEADS 12
#define HEAD 64
#define B_SZ 8
#define T_IMG 1024
#define T_CTX 256
#define FF_DIM 3072
#define ROWS_IMG (B_SZ * T_IMG)      // 8192
#define ROWS_CTX (B_SZ * T_CTX)     // 2048
#define BIGCOL (1 << 28)
#define PART_STRIDE (ROWS_IMG * D_EMB)   // split-K partial stride (elems)

typedef __bf16 bf16x8 __attribute__((ext_vector_type(8)));
typedef __bf16 bf16x4 __attribute__((ext_vector_type(4)));
typedef float f32x4 __attribute__((ext_vector_type(4)));

__device__ __forceinline__ void gld16(const void* g, void* l) {
    __builtin_amdgcn_global_load_lds(
        (const __attribute__((address_space(1))) unsigned int*)g,
        (__attribute__((address_space(3))) unsigned int*)l, 16, 0, 0);
}

// ---------------- W2 split-K reduce: X += P0 + P1 + b2 ----------------
__global__ __launch_bounds__(256) void reduce_w2_kernel(
    const __bf16* __restrict__ P, const float* __restrict__ b2,
    float* __restrict__ X) {
    int i = blockIdx.x * 256 + threadIdx.x;
    int base = i * 4;
    int col = base % D_EMB;
    bf16x4 p0 = *(const bf16x4*)&P[base];
    bf16x4 p1 = *(const bf16x4*)&P[PART_STRIDE + base];
    float4 x = *(float4*)&X[base];
    float4 bb = *(const float4*)&b2[col];
    x.x += (float)p0[0] + (float)p1[0] + bb.x;
    x.y += (float)p0[1] + (float)p1[1] + bb.y;
    x.z += (float)p0[2] + (float)p1[2] + bb.z;
    x.w += (float)p0[3] + (float)p1[3] + bb.w;
    *(float4*)&X[base] = x;
}

// ---------------- preproc device bodies (verified code, re-routed) ---------
__device__ __forceinline__ void transpose_cvt_body(
    float (*tile)[65], const float* __restrict__ src, __bf16* __restrict__ dst,
    int src_rows, int src_cols, int bx, int by, int tid) {
    int r0 = by * 64, c0 = bx * 64;
    int lr = tid >> 4, lc = (tid & 15) * 4;
#pragma unroll
    for (int i = 0; i < 4; i++) {
        float4 v = *(const float4*)&src[(size_t)(r0 + i * 16 + lr) * src_cols + c0 + lc];
        tile[i * 16 + lr][lc] = v.x; tile[i * 16 + lr][lc + 1] = v.y;
        tile[i * 16 + lr][lc + 2] = v.z; tile[i * 16 + lr][lc + 3] = v.w;
    }
    __syncthreads();
#pragma unroll
    for (int i = 0; i < 4; i++) {
        int cc = i * 16 + lr;
        int rr = (tid & 15) * 4;
        bf16x4 o;
#pragma unroll
        for (int j = 0; j < 4; j++) o[j] = (__bf16)tile[rr + j][cc];
        *(bf16x4*)&dst[(size_t)(c0 + cc) * src_rows + r0 + rr] = o;
    }
}

__device__ __forceinline__ void repack_body(
    float (*tile)[65],
    const float* __restrict__ Wq, const float* __restrict__ Wk,
    const float* __restrict__ Wv, const float* __restrict__ bq,
    const float* __restrict__ bk, const float* __restrict__ bv,
    __bf16* __restrict__ Wt, float* __restrict__ bp, int bx, int byy, int tid) {
    int which = byy / 12, h = byy - which * 12;
    int d0 = bx * 64;
    const float* W = (which == 0) ? Wq : ((which == 1) ? Wk : Wv);
    const float* src = W + ((size_t)h * D_EMB + d0) * HEAD;
    int lr = tid >> 4, lc = (tid & 15) * 4;
#pragma unroll
    for (int i = 0; i < 4; i++) {
        float4 v = *(const float4*)&src[(size_t)(i * 16 + lr) * HEAD + lc];
        tile[i * 16 + lr][lc] = v.x; tile[i * 16 + lr][lc + 1] = v.y;
        tile[i * 16 + lr][lc + 2] = v.z; tile[i * 16 + lr][lc + 3] = v.w;
    }
    __syncthreads();
#pragma unroll
    for (int i = 0; i < 4; i++) {
        int e = i * 16 + lr;
        int dd = (tid & 15) * 4;
        bf16x4 o;
#pragma unroll
        for (int j = 0; j < 4; j++) o[j] = (__bf16)tile[dd + j][e];
        *(bf16x4*)&Wt[(size_t)(which * 768 + h * 64 + e) * D_EMB + d0 + dd] = o;
    }
    if (bx == 0 && tid < 64) {
        const float* bb = (which == 0) ? bq : ((which == 1) ? bk : bv);
        bp[which * 768 + h * 64 + tid] = bb[h * 64 + tid];
    }
}

__device__ __forceinline__ void ln_body(const float* __restrict__ x,
                                        const float* __restrict__ lw,
                                        const float* __restrict__ lb,
                                        __bf16* __restrict__ y,
                                        int row, int tid) {
    __shared__ float red[8];
    __shared__ float stats[2];
    const float* xr = x + (size_t)row * D_EMB;
    float a0 = xr[tid], a1 = xr[tid + 256], a2 = xr[tid + 512];
    float s = a0 + a1 + a2;
    float ss = a0 * a0 + a1 * a1 + a2 * a2;
#pragma unroll
    for (int off = 32; off > 0; off >>= 1) {
        s += __shfl_down(s, off, 64);
        ss += __shfl_down(ss, off, 64);
    }
    int wv = tid >> 6, lane = tid & 63;
    if (lane == 0) { red[wv] = s; red[4 + wv] = ss; }
    __syncthreads();
    if (tid == 0) {
        float S = red[0] + red[1] + red[2] + red[3];
        float SS = red[4] + red[5] + red[6] + red[7];
        float mu = S * (1.0f / D_EMB);
        float var = SS * (1.0f / D_EMB) - mu * mu;
        stats[0] = mu;
        stats[1] = rsqrtf(var + 1e-5f);
    }
    __syncthreads();
    float mu = stats[0], rs = stats[1];
    __bf16* yr = y + (size_t)row * D_EMB;
    yr[tid]       = (__bf16)((a0 - mu) * rs * lw[tid]       + lb[tid]);
    yr[tid + 256] = (__bf16)((a1 - mu) * rs * lw[tid + 256] + lb[tid + 256]);
    yr[tid + 512] = (__bf16)((a2 - mu) * rs * lw[tid + 512] + lb[tid + 512]);
}

// ---------------- merged preprocessing + ln1: 1 dispatch -------------------
// [0,1536): ctx cvt | [1536,1968): repack self | [1968,2400): repack cross |
// [2400,2976): transpose W1 | [2976,3552): transpose W2 | [3552,11744): ln1
__global__ __launch_bounds__(256) void preproc_kernel(
    const float* __restrict__ ctx, __bf16* __restrict__ ctxb,
    const float* __restrict__ sWq, const float* __restrict__ sWk,
    const float* __restrict__ sWv, const float* __restrict__ sbq,
    const float* __restrict__ sbk, const float* __restrict__ sbv,
    __bf16* __restrict__ Wt, float* __restrict__ bp,
    const float* __restrict__ cWq, const float* __restrict__ cWk,
    const float* __restrict__ cWv, const float* __restrict__ cbq,
    const float* __restrict__ cbk, const float* __restrict__ cbv,
    __bf16* __restrict__ cWt, float* __restrict__ cbp,
    const float* __restrict__ W1, __bf16* __restrict__ W1t,
    const float* __restrict__ W2, __bf16* __restrict__ W2t,
    const float* __restrict__ img, const float* __restrict__ ln1w,
    const float* __restrict__ ln1b, __bf16* __restrict__ LNb) {
    __shared__ float tile[64][65];
    int bid = blockIdx.x;
    int tid = threadIdx.x;
    if (bid < 1536) {
        int i = bid * 256 + tid;                 // n4 = 393216, exact
        float4 v = ((const float4*)ctx)[i];
        __bf16* d = ctxb + i * 4;
        d[0] = (__bf16)v.x; d[1] = (__bf16)v.y; d[2] = (__bf16)v.z; d[3] = (__bf16)v.w;
    } else if (bid < 1968) {
        int vb = bid - 1536;
        repack_body(tile, sWq, sWk, sWv, sbq, sbk, sbv, Wt, bp,
                    vb % 12, vb / 12, tid);
    } else if (bid < 2400) {
        int vb = bid - 1968;
        repack_body(tile, cWq, cWk, cWv, cbq, cbk, cbv, cWt, cbp,
                    vb % 12, vb / 12, tid);
    } else if (bid < 2976) {
        int vb = bid - 2400;
        transpose_cvt_body(tile, W1, W1t, 768, FF_DIM, vb % 48, vb / 48, tid);
    } else if (bid < 3552) {
        int vb = bid - 2976;
        transpose_cvt_body(tile, W2, W2t, FF_DIM, 768, vb % 12, vb / 12, tid);
    } else {
        ln_body(img, ln1w, ln1b, LNb, bid - 3552, tid);
    }
}

// ---------------- layernorm over 768, bf16 output (ln2, ln3) ----------------
__global__ __launch_bounds__(256) void ln_kernel(const float* __restrict__ x,
                                                 const float* __restrict__ lw,
                                                 const float* __restrict__ lb,
                                                 __bf16* __restrict__ y) {
    ln_body(x, lw, lb, y, blockIdx.x, threadIdx.x);
}

// ---------------- bf16 MFMA GEMM body (B^T layout), swapped operands -------
// BK=64, XOR-swizzled LDS (zero bank conflicts), compile-time LDA/LDB.
__device__ __forceinline__ bf16x8 lds_frag(const __bf16* h, int row, int kk, int quad) {
    int off = (kk * 32 + quad * 8) ^ ((row & 7) << 3);    // swizzled read
    return *(const bf16x8*)&h[row * 64 + off];
}

template <int LDA, int LDB>
__device__ __forceinline__ void gemm_body(
    int bx, int by, int kz, int tid,
    const __bf16* __restrict__ A,
    const __bf16* __restrict__ Bt,
    const float* __restrict__ bias,
    __bf16* __restrict__ Cb, int ldc,
    int Kc, int act, int qlimit,
    __bf16* __restrict__ VTout, int vtok, int vcol0, int kcol0, int kcol1,
    float* __restrict__ Xres,
    __bf16* As, __bf16* Bs) {
    int w = tid >> 6, lane = tid & 63;
    int c = lane & 15, quad = lane >> 4;
    int wm = (w >> 1) * 64, wn = (w & 1) * 64;

    f32x4 acc[4][4];
#pragma unroll
    for (int i = 0; i < 4; i++)
#pragma unroll
        for (int j = 0; j < 4; j++) acc[i][j] = (f32x4){0.f, 0.f, 0.f, 0.f};

    // staging: 256 threads x 4 x 16B per operand tile (128 rows x 64 cols).
    // source col pre-swizzled with the row-XOR so linear LDS + swizzled read
    // = identity (verified r8-r17, 0 conflicts).
    int srow = tid >> 3;                                   // 0..31
    int scol = ((tid & 7) * 8) ^ ((srow & 7) * 8);         // inverse swizzle
    const __bf16* Ag = A + (size_t)(by * 128 + srow) * LDA + (size_t)kz * Kc + scol;
    const __bf16* Bg = Bt + (size_t)(bx * 128 + srow) * LDB + (size_t)kz * Kc + scol;
    char* AsB = (char*)As + w * 1024;
    char* BsB = (char*)Bs + w * 1024;

    for (int k0 = 0; k0 < Kc; k0 += 64) {
#pragma unroll
        for (int j = 0; j < 4; j++) {
            gld16(Ag + (size_t)(j * 32) * LDA + k0, AsB + j * 4096);
            gld16(Bg + (size_t)(j * 32) * LDB + k0, BsB + j * 4096);
        }
        __syncthreads();
#pragma unroll
        for (int kk = 0; kk < 2; kk++) {
            bf16x8 af[4], bfr[4];
#pragma unroll
            for (int mi = 0; mi < 4; mi++)
                af[mi] = lds_frag(As, wm + mi * 16 + c, kk, quad);
#pragma unroll
            for (int ni = 0; ni < 4; ni++)
                bfr[ni] = lds_frag(Bs, wn + ni * 16 + c, kk, quad);
#pragma unroll
            for (int mi = 0; mi < 4; mi++)
#pragma unroll
                for (int ni = 0; ni < 4; ni++)
                    acc[mi][ni] = __builtin_amdgcn_mfma_f32_16x16x32_bf16(
                        bfr[ni], af[mi], acc[mi][ni], 0, 0, 0);   // swapped: C^T
        }
        __syncthreads();
    }

#pragma unroll
    for (int mi = 0; mi < 4; mi++) {
#pragma unroll
        for (int ni = 0; ni < 4; ni++) {
            int row = by * 128 + wm + mi * 16 + c;                 // C row
            int colbase = bx * 128 + wn + ni * 16 + quad * 4;      // 4 consecutive C cols
            float bvv[4] = {0.f, 0.f, 0.f, 0.f};
            if (bias && kz == 0) {
                float4 b4 = *(const float4*)&bias[colbase];
                bvv[0] = b4.x; bvv[1] = b4.y; bvv[2] = b4.z; bvv[3] = b4.w;
            }
            float qs = (colbase < qlimit) ? 0.125f : 1.0f;   // qlimit%4==0 -> uniform
            float v[4];
#pragma unroll
            for (int r = 0; r < 4; r++) {
                float t = (acc[mi][ni][r] + bvv[r]) * qs;
                if (act == 1) t = t / (1.0f + __expf(-t));
                v[r] = t;
            }
            if (Xres) {
                float4 x4 = *(float4*)&Xres[(size_t)row * D_EMB + colbase];
                x4.x += v[0]; x4.y += v[1]; x4.z += v[2]; x4.w += v[3];
                *(float4*)&Xres[(size_t)row * D_EMB + colbase] = x4;
            } else if (VTout && colbase >= vcol0) {
                int hc = colbase - vcol0;
                int hh = hc >> 6, ebase = hc & 63;
                int tok = row;
#pragma unroll
                for (int r = 0; r < 4; r++) {
                    int e = ebase + r;
                    int sl = ((((tok >> 3) & 7) ^ (e & 7)) << 3) | (tok & 7);
                    VTout[(size_t)(hh * 64 + e) * vtok + (tok & ~63) + sl] = (__bf16)v[r];
                }
            } else if (colbase >= kcol0 && colbase < kcol1) {
                int hc = colbase - kcol0;
                int hh = hc >> 6, ebase = hc & 63;
                int tok = row;
                int es = (((ebase >> 3) ^ (tok & 7)) << 3) | (ebase & 7);
                bf16x4 pv;
#pragma unroll
                for (int r = 0; r < 4; r++) pv[r] = (__bf16)v[r];
                *(bf16x4*)&Cb[(size_t)tok * ldc + kcol0 + hh * 64 + es] = pv;
            } else {
                __bf16* dst = Cb + (size_t)kz * PART_STRIDE;
                bf16x4 pv;
#pragma unroll
                for (int r = 0; r < 4; r++) pv[r] = (__bf16)v[r];
                *(bf16x4*)&dst[(size_t)row * ldc + colbase] = pv;
            }
        }
    }
}

template <int LDA, int LDB>
__global__ __launch_bounds__(256) void mfma_gemm_bt(
    const __bf16* __restrict__ A,
    const __bf16* __restrict__ Bt,
    const float* __restrict__ bias,
    __bf16* __restrict__ Cb, int ldc,
    int Kc, int act, int qlimit,
    __bf16* __restrict__ VTout, int vtok, int vcol0, int kcol0, int kcol1,
    float* __restrict__ Xres) {
    __shared__ __bf16 As[128 * 64];   // 16 KiB
    __shared__ __bf16 Bs[128 * 64];   // 16 KiB
    // bijective XCD grouping swizzle (requires nwg%8==0; true for all grids)
    int gx = gridDim.x;
    int nwg = gx * gridDim.y;
    int orig = blockIdx.y * gx + blockIdx.x;
    int swz = (orig & 7) * (nwg >> 3) + (orig >> 3);
    gemm_body<LDA, LDB>(swz % gx, swz / gx, blockIdx.z, threadIdx.x,
                        A, Bt, bias, Cb, ldc, Kc, act, qlimit,
                        VTout, vtok, vcol0, kcol0, kcol1, Xres, As, Bs);
}

// ---------------- merged cross-attn GEMMs: Qc (384 blks) + KVc (192 blks) --
__global__ __launch_bounds__(256) void cross_gemm_kernel(
    const __bf16* __restrict__ LNb, const __bf16* __restrict__ cWt,
    const float* __restrict__ cbp, const __bf16* __restrict__ ctxb,
    __bf16* __restrict__ Qc, __bf16* __restrict__ KVc,
    __bf16* __restrict__ VTc) {
    __shared__ __bf16 As[128 * 64];
    __shared__ __bf16 Bs[128 * 64];
    int bid = blockIdx.x;
    if (bid < 384) {
        // Qc: M=8192 N=768 K=768, grid 6x64, XCD swizzle within range
        int swz = (bid & 7) * 48 + (bid >> 3);
        gemm_body<768, 768>(swz % 6, swz / 6, 0, threadIdx.x,
                            LNb, cWt, cbp, Qc, 768, D_EMB, 0, 768,
                            nullptr, 0, BIGCOL, BIGCOL, BIGCOL, nullptr, As, Bs);
    } else {
        // KVc: M=2048 N=1536 K=768, grid 12x16 ((bid-384)%8 == bid%8, 384%8==0)
        int b2 = bid - 384;
        int swz = (b2 & 7) * 24 + (b2 >> 3);
        gemm_body<768, 768>(swz % 12, swz / 12, 0, threadIdx.x,
                            ctxb, cWt + (size_t)768 * 768, cbp + 768,
                            KVc, 1536, D_EMB, 0, 0,
                            VTc, ROWS_CTX, 768, 0, 768, nullptr, As, Bs);
    }
}

// ---------------- flash MFMA attention, 128 q/block ------------------------
// T14 async-STAGE: K/V reg-staged; next tile's loads issued after barrier(B),
// covered by the full QK^T+SM+PV phase (the next __syncthreads drains them).
// 2 barriers/tile ("P visible" barrier deleted: P rows are same-wave only).
// Block mapping XCD-grouped: bh = n%96, qt = n/96. Xin: if non-null,
// X[i] = Xin[i] + O (first residual); else X[i] += O.
__global__ __launch_bounds__(128, 2) void mfma_attn(
    const __bf16* __restrict__ Q, int qld,
    const __bf16* __restrict__ Kp, int kld,
    const __bf16* __restrict__ VTg, int vtok,
    int kv_tokens, float* __restrict__ X, const float* __restrict__ Xin) {
    __shared__ __bf16 Kt[64 * 64];     // [s][d] swizzled granules
    __shared__ __bf16 VT[80 * 64];     // [e][s] swizzled; rows 64..79 ones/zeros
    __shared__ __bf16 Ps[128 * 76];    // [q][s] stride 76; also Q staging (stride 64)
    int tid = threadIdx.x;
    int bh = blockIdx.x % 96;          // XCD-grouping: n%8 == bh%8
    int qt = blockIdx.x / 96;
    int b = bh / N_HEADS, h = bh - b * N_HEADS;
    int w = tid >> 6, lane = tid & 63, c = lane & 15, quad = lane >> 4;
    int q0 = qt * 128;

    for (int i = tid; i < 16 * 64; i += 128)
        VT[64 * 64 + i] = (i < 64) ? (__bf16)1.0f : (__bf16)0.0f;

    // per-thread K/V global bases (identical addresses to old gld16 path)
    const __bf16* Kg = Kp + (size_t)(b * kv_tokens + (tid >> 3)) * kld
                       + h * HEAD + (tid & 7) * 8;
    const __bf16* Vg = VTg + (size_t)(h * HEAD + (tid >> 3)) * vtok
                       + b * kv_tokens + (tid & 7) * 8;
    bf16x8 kr[4], vr[4], krn[4], vrn[4];
#pragma unroll
    for (int j = 0; j < 4; j++) {        // tile 0 prefetch (covered by Q stage)
        kr[j] = *(const bf16x8*)(Kg + (size_t)(j * 16) * kld);
        vr[j] = *(const bf16x8*)(Vg + (size_t)(j * 16) * vtok);
    }

    {
        const __bf16* Qg = Q + (size_t)(b * T_IMG + q0 + (tid >> 3)) * qld
                           + h * HEAD + (tid & 7) * 8;
        char* QsB = (char*)Ps + w * 1024;
#pragma unroll
        for (int j = 0; j < 8; j++)
            gld16(Qg + (size_t)j * 16 * qld, QsB + j * 2048);
    }
    __syncthreads();
    bf16x8 qa[4][2];
#pragma unroll
    for (int st = 0; st < 4; st++)
#pragma unroll
        for (int ch = 0; ch < 2; ch++)
            qa[st][ch] = *(const bf16x8*)&Ps[(w * 64 + st * 16 + c) * 64 + ch * 32 + quad * 8];

    f32x4 o[4][5];
#pragma unroll
    for (int st = 0; st < 4; st++)
#pragma unroll
        for (int ut = 0; ut < 5; ut++) o[st][ut] = (f32x4){0.f, 0.f, 0.f, 0.f};

    int ntiles = kv_tokens >> 6;
    for (int t = 0; t < ntiles; t++) {
        __syncthreads();   // (A) LDS free (prev PV + Q-frag reads drained);
                           //     also completes the in-flight kr/vr loads
#pragma unroll
        for (int j = 0; j < 4; j++) {
            *(bf16x8*)&Kt[tid * 8 + j * 1024] = kr[j];
            *(bf16x8*)&VT[tid * 8 + j * 1024] = vr[j];
        }
        __syncthreads();   // (B) K/V visible to both waves
        if (t + 1 < ntiles) {   // prefetch t+1: in flight until next (A)
            const __bf16* Kg2 = Kg + (size_t)((t + 1) * 64) * kld;
            const __bf16* Vg2 = Vg + (t + 1) * 64;
#pragma unroll
            for (int j = 0; j < 4; j++) {
                krn[j] = *(const bf16x8*)(Kg2 + (size_t)(j * 16) * kld);
                vrn[j] = *(const bf16x8*)(Vg2 + (size_t)(j * 16) * vtok);
            }
        }

        bf16x8 kb[4][2];
#pragma unroll
        for (int nt = 0; nt < 4; nt++)
#pragma unroll
            for (int ch = 0; ch < 2; ch++)
                kb[nt][ch] = *(const bf16x8*)&Kt[(nt * 16 + c) * 64
                                + (((ch * 4 + quad) ^ (c & 7)) << 3)];
#pragma unroll
        for (int st = 0; st < 4; st++) {
            f32x4 s[4];
#pragma unroll
            for (int nt = 0; nt < 4; nt++) {
                s[nt] = (f32x4){0.f, 0.f, 0.f, 0.f};
                s[nt] = __builtin_amdgcn_mfma_f32_16x16x32_bf16(kb[nt][0], qa[st][0], s[nt], 0, 0, 0);
                s[nt] = __builtin_amdgcn_mfma_f32_16x16x32_bf16(kb[nt][1], qa[st][1], s[nt], 0, 0, 0);
            }
#pragma unroll
            for (int nt = 0; nt < 4; nt++) {
                bf16x4 pk;
#pragma unroll
                for (int r = 0; r < 4; r++) pk[r] = (__bf16)__expf(s[nt][r]);
                *(bf16x4*)&Ps[(size_t)(w * 64 + st * 16 + c) * 76 + nt * 16 + quad * 4] = pk;
            }
        }
        // NO barrier: P rows [w*64, w*64+64) are written and read by the SAME
        // wave only -> compiler-ordered via lgkmcnt (in-order DS ops).

        bf16x8 vb[5][2];
#pragma unroll
        for (int ut = 0; ut < 5; ut++)
#pragma unroll
            for (int ch = 0; ch < 2; ch++)
                vb[ut][ch] = *(const bf16x8*)&VT[(ut * 16 + c) * 64
                                + (((ch * 4 + quad) ^ (c & 7)) << 3)];
#pragma unroll
        for (int st = 0; st < 4; st++) {
            bf16x8 pa0 = *(const bf16x8*)&Ps[(w * 64 + st * 16 + c) * 76 + quad * 8];
            bf16x8 pa1 = *(const bf16x8*)&Ps[(w * 64 + st * 16 + c) * 76 + 32 + quad * 8];
#pragma unroll
            for (int ut = 0; ut < 5; ut++) {
                o[st][ut] = __builtin_amdgcn_mfma_f32_16x16x32_bf16(pa0, vb[ut][0], o[st][ut], 0, 0, 0);
                o[st][ut] = __builtin_amdgcn_mfma_f32_16x16x32_bf16(pa1, vb[ut][1], o[st][ut], 0, 0, 0);
            }
        }
        if (t + 1 < ntiles) {
#pragma unroll
            for (int j = 0; j < 4; j++) { kr[j] = krn[j]; vr[j] = vrn[j]; }
        }
    }

#pragma unroll
    for (int st = 0; st < 4; st++) {
        float lr[4];
#pragma unroll
        for (int r = 0; r < 4; r++) lr[r] = __shfl(o[st][4][r], lane & 48, 64);
#pragma unroll
        for (int ut = 0; ut < 4; ut++) {
#pragma unroll
            for (int r = 0; r < 4; r++) {
                int row = b * T_IMG + q0 + w * 64 + st * 16 + quad * 4 + r;
                int col = h * HEAD + ut * 16 + c;
                size_t idx = (size_t)row * D_EMB + col;
                float base = Xin ? Xin[idx] : X[idx];
                X[idx] = base + o[st][ut][r] / lr[r];
            }
        }
    }
}

// ---------------------------------------------------------------------------
extern "C" void kernel_launch(void* const* d_in, const int* in_sizes, int n_in,
                              void* d_out, int out_size, void* d_ws, size_t ws_size,
                              hipStream_t stream) {
    const float* img  = (const float*)d_in[0];
    const float* ctx  = (const float*)d_in[1];
    const float* ln1w = (const float*)d_in[2];  const float* ln1b = (const float*)d_in[3];
    const float* sWq  = (const float*)d_in[4];  const float* sbq  = (const float*)d_in[5];
    const float* sWk  = (const float*)d_in[6];  const float* sbk  = (const float*)d_in[7];
    const float* sWv  = (const float*)d_in[8];  const float* sbv  = (const float*)d_in[9];
    const float* ln2w = (const float*)d_in[10]; const float* ln2b = (const float*)d_in[11];
    const float* cWq  = (const float*)d_in[12]; const float* cbq  = (const float*)d_in[13];
    const float* cWk  = (const float*)d_in[14]; const float* cbk  = (const float*)d_in[15];
    const float* cWv  = (const float*)d_in[16]; const float* cbv  = (const float*)d_in[17];
    const float* ln3w = (const float*)d_in[18]; const float* ln3b = (const float*)d_in[19];
    const float* W1   = (const float*)d_in[20]; const float* b1   = (const float*)d_in[21];
    const float* W2   = (const float*)d_in[22]; const float* b2   = (const float*)d_in[23];

    float* X = (float*)d_out;

    char* p = (char*)d_ws;
    __bf16* LNb  = (__bf16*)p; p += (size_t)ROWS_IMG * D_EMB * 2;       // 12.6 MB
    __bf16* VTg  = (__bf16*)p; p += (size_t)12 * 64 * ROWS_IMG * 2;     // 12.6 MB
    __bf16* BIG  = (__bf16*)p; p += (size_t)ROWS_IMG * FF_DIM * 2;      // 50.3 MB
    __bf16* ctxb = (__bf16*)p; p += (size_t)ROWS_CTX * D_EMB * 2;       // 3.1 MB
    __bf16* Wt   = (__bf16*)p; p += (size_t)2304 * 768 * 2;             // 3.5 MB
    __bf16* cWt  = (__bf16*)p; p += (size_t)2304 * 768 * 2;             // 3.5 MB
    __bf16* W1t  = (__bf16*)p; p += (size_t)FF_DIM * 768 * 2;           // 4.7 MB
    __bf16* W2t  = (__bf16*)p; p += (size_t)768 * FF_DIM * 2;           // 4.7 MB
    __bf16* VTc  = (__bf16*)p; p += (size_t)12 * 64 * ROWS_CTX * 2;     // 3.1 MB
    float*  bp   = (float*)p;  p += 2304 * 4;
    float*  cbp  = (float*)p;  p += 2304 * 4;
    __bf16* Pk   = LNb;   // split-K partials overlay (LNb+VTg dead by stage 3)
    __bf16* QKVb = BIG;
    __bf16* Qc   = BIG;
    __bf16* KVc  = BIG + (size_t)ROWS_IMG * 768;
    __bf16* FFh  = BIG;

    // ---- all preprocessing + ln1 in ONE dispatch ----
    preproc_kernel<<<11744, 256, 0, stream>>>(
        ctx, ctxb,
        sWq, sWk, sWv, sbq, sbk, sbv, Wt, bp,
        cWq, cWk, cWv, cbq, cbk, cbv, cWt, cbp,
        W1, W1t, W2, W2t,
        img, ln1w, ln1b, LNb);

    // ---- stage 1: self attention (attn1 fuses X = img + O) ----
    mfma_gemm_bt<768, 768><<<dim3(2304 / 128, ROWS_IMG / 128), 256, 0, stream>>>(
        LNb, Wt, bp, QKVb, 2304, D_EMB, 0, 768,
        VTg, ROWS_IMG, 1536, 768, 1536, nullptr);
    mfma_attn<<<96 * 8, 128, 0, stream>>>(
        QKVb, 2304, QKVb + 768, 2304, VTg, ROWS_IMG, T_IMG, X, img);

    // ---- stage 2: cross attention (Qc + KVc in ONE dispatch) ----
    ln_kernel<<<ROWS_IMG, 256, 0, stream>>>(X, ln2w, ln2b, LNb);
    cross_gemm_kernel<<<576, 256, 0, stream>>>(LNb, cWt, cbp, ctxb, Qc, KVc, VTc);
    mfma_attn<<<96 * 8, 128, 0, stream>>>(
        Qc, 768, KVc, 1536, VTc, ROWS_CTX, T_CTX, X, nullptr);

    // ---- stage 3: MLP (W1 single pass; W2 split-K x2 + fused reduce) ----
    ln_kernel<<<ROWS_IMG, 256, 0, stream>>>(X, ln3w, ln3b, LNb);
    mfma_gemm_bt<768, 768><<<dim3(FF_DIM / 128, ROWS_IMG / 128), 256, 0, stream>>>(
        LNb, W1t, b1, FFh, FF_DIM, D_EMB, 1, 0,
        nullptr, 0, BIGCOL, BIGCOL, BIGCOL, nullptr);
    mfma_gemm_bt<3072, 3072><<<dim3(768 / 128, ROWS_IMG / 128, 2), 256, 0, stream>>>(
        FFh, W2t, nullptr, Pk, D_EMB, 1536, 0, 0,
        nullptr, 0, BIGCOL, BIGCOL, BIGCOL, nullptr);
    reduce_w2_kernel<<<ROWS_IMG * D_EMB / 4 / 256, 256, 0, stream>>>(Pk, b2, X);
}

// Round 15
// 453.905 us; speedup vs baseline: 1.0605x; 1.0102x over previous
//
#include <hip/hip_runtime.h>
#include <hip/hip_bf16.h>

// ---------------------------------------------------------------------------
// DiT block, bf16 MFMA, round 21.
// De-risk after two container failures (r19 alias bug, r20 infra x2): revert
// to the r18 PASSING structure (458.6us) + ONLY the correctness-neutral T5
// setprio around attn MFMA clusters (m191: +4-7% on attn; not on GEMM, m190).
// KVc merge shelved; stage 2 back to the r17/r18 cross_gemm (Qc+KVc ranges),
// KVc at its harness-proven r18 location (sequential lifetime, no alias).
// Kept from r18: T14 async-STAGE attn (2 barriers/tile), preproc+ln1 merge,
// templated GEMMs, split-K W2, XCD swizzles, zero-conflict LDS.
// ---------------------------------------------------------------------------

#define D_EMB 768
#define N_HEADS 12
#define HEAD 64
#define B_SZ 8
#define T_IMG 1024
#define T_CTX 256
#define FF_DIM 3072
#define ROWS_IMG (B_SZ * T_IMG)      // 8192
#define ROWS_CTX (B_SZ * T_CTX)     // 2048
#define BIGCOL (1 << 28)
#define PART_STRIDE (ROWS_IMG * D_EMB)   // split-K partial stride (elems)

typedef __bf16 bf16x8 __attribute__((ext_vector_type(8)));
typedef __bf16 bf16x4 __attribute__((ext_vector_type(4)));
typedef float f32x4 __attribute__((ext_vector_type(4)));

__device__ __forceinline__ void gld16(const void* g, void* l) {
    __builtin_amdgcn_global_load_lds(
        (const __attribute__((address_space(1))) unsigned int*)g,
        (__attribute__((address_space(3))) unsigned int*)l, 16, 0, 0);
}

// ---------------- W2 split-K reduce: X += P0 + P1 + b2 ----------------
__global__ __launch_bounds__(256) void reduce_w2_kernel(
    const __bf16* __restrict__ P, const float* __restrict__ b2,
    float* __restrict__ X) {
    int i = blockIdx.x * 256 + threadIdx.x;
    int base = i * 4;
    int col = base % D_EMB;
    bf16x4 p0 = *(const bf16x4*)&P[base];
    bf16x4 p1 = *(const bf16x4*)&P[PART_STRIDE + base];
    float4 x = *(float4*)&X[base];
    float4 bb = *(const float4*)&b2[col];
    x.x += (float)p0[0] + (float)p1[0] + bb.x;
    x.y += (float)p0[1] + (float)p1[1] + bb.y;
    x.z += (float)p0[2] + (float)p1[2] + bb.z;
    x.w += (float)p0[3] + (float)p1[3] + bb.w;
    *(float4*)&X[base] = x;
}

// ---------------- preproc device bodies (verified code, re-routed) ---------
__device__ __forceinline__ void transpose_cvt_body(
    float (*tile)[65], const float* __restrict__ src, __bf16* __restrict__ dst,
    int src_rows, int src_cols, int bx, int by, int tid) {
    int r0 = by * 64, c0 = bx * 64;
    int lr = tid >> 4, lc = (tid & 15) * 4;
#pragma unroll
    for (int i = 0; i < 4; i++) {
        float4 v = *(const float4*)&src[(size_t)(r0 + i * 16 + lr) * src_cols + c0 + lc];
        tile[i * 16 + lr][lc] = v.x; tile[i * 16 + lr][lc + 1] = v.y;
        tile[i * 16 + lr][lc + 2] = v.z; tile[i * 16 + lr][lc + 3] = v.w;
    }
    __syncthreads();
#pragma unroll
    for (int i = 0; i < 4; i++) {
        int cc = i * 16 + lr;
        int rr = (tid & 15) * 4;
        bf16x4 o;
#pragma unroll
        for (int j = 0; j < 4; j++) o[j] = (__bf16)tile[rr + j][cc];
        *(bf16x4*)&dst[(size_t)(c0 + cc) * src_rows + r0 + rr] = o;
    }
}

__device__ __forceinline__ void repack_body(
    float (*tile)[65],
    const float* __restrict__ Wq, const float* __restrict__ Wk,
    const float* __restrict__ Wv, const float* __restrict__ bq,
    const float* __restrict__ bk, const float* __restrict__ bv,
    __bf16* __restrict__ Wt, float* __restrict__ bp, int bx, int byy, int tid) {
    int which = byy / 12, h = byy - which * 12;
    int d0 = bx * 64;
    const float* W = (which == 0) ? Wq : ((which == 1) ? Wk : Wv);
    const float* src = W + ((size_t)h * D_EMB + d0) * HEAD;
    int lr = tid >> 4, lc = (tid & 15) * 4;
#pragma unroll
    for (int i = 0; i < 4; i++) {
        float4 v = *(const float4*)&src[(size_t)(i * 16 + lr) * HEAD + lc];
        tile[i * 16 + lr][lc] = v.x; tile[i * 16 + lr][lc + 1] = v.y;
        tile[i * 16 + lr][lc + 2] = v.z; tile[i * 16 + lr][lc + 3] = v.w;
    }
    __syncthreads();
#pragma unroll
    for (int i = 0; i < 4; i++) {
        int e = i * 16 + lr;
        int dd = (tid & 15) * 4;
        bf16x4 o;
#pragma unroll
        for (int j = 0; j < 4; j++) o[j] = (__bf16)tile[dd + j][e];
        *(bf16x4*)&Wt[(size_t)(which * 768 + h * 64 + e) * D_EMB + d0 + dd] = o;
    }
    if (bx == 0 && tid < 64) {
        const float* bb = (which == 0) ? bq : ((which == 1) ? bk : bv);
        bp[which * 768 + h * 64 + tid] = bb[h * 64 + tid];
    }
}

__device__ __forceinline__ void ln_body(const float* __restrict__ x,
                                        const float* __restrict__ lw,
                                        const float* __restrict__ lb,
                                        __bf16* __restrict__ y,
                                        int row, int tid) {
    __shared__ float red[8];
    __shared__ float stats[2];
    const float* xr = x + (size_t)row * D_EMB;
    float a0 = xr[tid], a1 = xr[tid + 256], a2 = xr[tid + 512];
    float s = a0 + a1 + a2;
    float ss = a0 * a0 + a1 * a1 + a2 * a2;
#pragma unroll
    for (int off = 32; off > 0; off >>= 1) {
        s += __shfl_down(s, off, 64);
        ss += __shfl_down(ss, off, 64);
    }
    int wv = tid >> 6, lane = tid & 63;
    if (lane == 0) { red[wv] = s; red[4 + wv] = ss; }
    __syncthreads();
    if (tid == 0) {
        float S = red[0] + red[1] + red[2] + red[3];
        float SS = red[4] + red[5] + red[6] + red[7];
        float mu = S * (1.0f / D_EMB);
        float var = SS * (1.0f / D_EMB) - mu * mu;
        stats[0] = mu;
        stats[1] = rsqrtf(var + 1e-5f);
    }
    __syncthreads();
    float mu = stats[0], rs = stats[1];
    __bf16* yr = y + (size_t)row * D_EMB;
    yr[tid]       = (__bf16)((a0 - mu) * rs * lw[tid]       + lb[tid]);
    yr[tid + 256] = (__bf16)((a1 - mu) * rs * lw[tid + 256] + lb[tid + 256]);
    yr[tid + 512] = (__bf16)((a2 - mu) * rs * lw[tid + 512] + lb[tid + 512]);
}

// ---------------- merged preprocessing + ln1: 1 dispatch -------------------
// [0,1536): ctx cvt | [1536,1968): repack self | [1968,2400): repack cross |
// [2400,2976): transpose W1 | [2976,3552): transpose W2 | [3552,11744): ln1
__global__ __launch_bounds__(256) void preproc_kernel(
    const float* __restrict__ ctx, __bf16* __restrict__ ctxb,
    const float* __restrict__ sWq, const float* __restrict__ sWk,
    const float* __restrict__ sWv, const float* __restrict__ sbq,
    const float* __restrict__ sbk, const float* __restrict__ sbv,
    __bf16* __restrict__ Wt, float* __restrict__ bp,
    const float* __restrict__ cWq, const float* __restrict__ cWk,
    const float* __restrict__ cWv, const float* __restrict__ cbq,
    const float* __restrict__ cbk, const float* __restrict__ cbv,
    __bf16* __restrict__ cWt, float* __restrict__ cbp,
    const float* __restrict__ W1, __bf16* __restrict__ W1t,
    const float* __restrict__ W2, __bf16* __restrict__ W2t,
    const float* __restrict__ img, const float* __restrict__ ln1w,
    const float* __restrict__ ln1b, __bf16* __restrict__ LNb) {
    __shared__ float tile[64][65];
    int bid = blockIdx.x;
    int tid = threadIdx.x;
    if (bid < 1536) {
        int i = bid * 256 + tid;                 // n4 = 393216, exact
        float4 v = ((const float4*)ctx)[i];
        __bf16* d = ctxb + i * 4;
        d[0] = (__bf16)v.x; d[1] = (__bf16)v.y; d[2] = (__bf16)v.z; d[3] = (__bf16)v.w;
    } else if (bid < 1968) {
        int vb = bid - 1536;
        repack_body(tile, sWq, sWk, sWv, sbq, sbk, sbv, Wt, bp,
                    vb % 12, vb / 12, tid);
    } else if (bid < 2400) {
        int vb = bid - 1968;
        repack_body(tile, cWq, cWk, cWv, cbq, cbk, cbv, cWt, cbp,
                    vb % 12, vb / 12, tid);
    } else if (bid < 2976) {
        int vb = bid - 2400;
        transpose_cvt_body(tile, W1, W1t, 768, FF_DIM, vb % 48, vb / 48, tid);
    } else if (bid < 3552) {
        int vb = bid - 2976;
        transpose_cvt_body(tile, W2, W2t, FF_DIM, 768, vb % 12, vb / 12, tid);
    } else {
        ln_body(img, ln1w, ln1b, LNb, bid - 3552, tid);
    }
}

// ---------------- layernorm over 768, bf16 output (ln2, ln3) ----------------
__global__ __launch_bounds__(256) void ln_kernel(const float* __restrict__ x,
                                                 const float* __restrict__ lw,
                                                 const float* __restrict__ lb,
                                                 __bf16* __restrict__ y) {
    ln_body(x, lw, lb, y, blockIdx.x, threadIdx.x);
}

// ---------------- bf16 MFMA GEMM body (B^T layout), swapped operands -------
// BK=64, XOR-swizzled LDS (zero bank conflicts), compile-time LDA/LDB.
__device__ __forceinline__ bf16x8 lds_frag(const __bf16* h, int row, int kk, int quad) {
    int off = (kk * 32 + quad * 8) ^ ((row & 7) << 3);    // swizzled read
    return *(const bf16x8*)&h[row * 64 + off];
}

template <int LDA, int LDB>
__device__ __forceinline__ void gemm_body(
    int bx, int by, int kz, int tid,
    const __bf16* __restrict__ A,
    const __bf16* __restrict__ Bt,
    const float* __restrict__ bias,
    __bf16* __restrict__ Cb, int ldc,
    int Kc, int act, int qlimit,
    __bf16* __restrict__ VTout, int vtok, int vcol0, int kcol0, int kcol1,
    float* __restrict__ Xres,
    __bf16* As, __bf16* Bs) {
    int w = tid >> 6, lane = tid & 63;
    int c = lane & 15, quad = lane >> 4;
    int wm = (w >> 1) * 64, wn = (w & 1) * 64;

    f32x4 acc[4][4];
#pragma unroll
    for (int i = 0; i < 4; i++)
#pragma unroll
        for (int j = 0; j < 4; j++) acc[i][j] = (f32x4){0.f, 0.f, 0.f, 0.f};

    // staging: 256 threads x 4 x 16B per operand tile (128 rows x 64 cols).
    // source col pre-swizzled with the row-XOR so linear LDS + swizzled read
    // = identity (verified r8-r18, 0 conflicts).
    int srow = tid >> 3;                                   // 0..31
    int scol = ((tid & 7) * 8) ^ ((srow & 7) * 8);         // inverse swizzle
    const __bf16* Ag = A + (size_t)(by * 128 + srow) * LDA + (size_t)kz * Kc + scol;
    const __bf16* Bg = Bt + (size_t)(bx * 128 + srow) * LDB + (size_t)kz * Kc + scol;
    char* AsB = (char*)As + w * 1024;
    char* BsB = (char*)Bs + w * 1024;

    for (int k0 = 0; k0 < Kc; k0 += 64) {
#pragma unroll
        for (int j = 0; j < 4; j++) {
            gld16(Ag + (size_t)(j * 32) * LDA + k0, AsB + j * 4096);
            gld16(Bg + (size_t)(j * 32) * LDB + k0, BsB + j * 4096);
        }
        __syncthreads();
#pragma unroll
        for (int kk = 0; kk < 2; kk++) {
            bf16x8 af[4], bfr[4];
#pragma unroll
            for (int mi = 0; mi < 4; mi++)
                af[mi] = lds_frag(As, wm + mi * 16 + c, kk, quad);
#pragma unroll
            for (int ni = 0; ni < 4; ni++)
                bfr[ni] = lds_frag(Bs, wn + ni * 16 + c, kk, quad);
#pragma unroll
            for (int mi = 0; mi < 4; mi++)
#pragma unroll
                for (int ni = 0; ni < 4; ni++)
                    acc[mi][ni] = __builtin_amdgcn_mfma_f32_16x16x32_bf16(
                        bfr[ni], af[mi], acc[mi][ni], 0, 0, 0);   // swapped: C^T
        }
        __syncthreads();
    }

#pragma unroll
    for (int mi = 0; mi < 4; mi++) {
#pragma unroll
        for (int ni = 0; ni < 4; ni++) {
            int row = by * 128 + wm + mi * 16 + c;                 // C row
            int colbase = bx * 128 + wn + ni * 16 + quad * 4;      // 4 consecutive C cols
            float bvv[4] = {0.f, 0.f, 0.f, 0.f};
            if (bias && kz == 0) {
                float4 b4 = *(const float4*)&bias[colbase];
                bvv[0] = b4.x; bvv[1] = b4.y; bvv[2] = b4.z; bvv[3] = b4.w;
            }
            float qs = (colbase < qlimit) ? 0.125f : 1.0f;   // qlimit%4==0 -> uniform
            float v[4];
#pragma unroll
            for (int r = 0; r < 4; r++) {
                float t = (acc[mi][ni][r] + bvv[r]) * qs;
                if (act == 1) t = t / (1.0f + __expf(-t));
                v[r] = t;
            }
            if (Xres) {
                float4 x4 = *(float4*)&Xres[(size_t)row * D_EMB + colbase];
                x4.x += v[0]; x4.y += v[1]; x4.z += v[2]; x4.w += v[3];
                *(float4*)&Xres[(size_t)row * D_EMB + colbase] = x4;
            } else if (VTout && colbase >= vcol0) {
                int hc = colbase - vcol0;
                int hh = hc >> 6, ebase = hc & 63;
                int tok = row;
#pragma unroll
                for (int r = 0; r < 4; r++) {
                    int e = ebase + r;
                    int sl = ((((tok >> 3) & 7) ^ (e & 7)) << 3) | (tok & 7);
                    VTout[(size_t)(hh * 64 + e) * vtok + (tok & ~63) + sl] = (__bf16)v[r];
                }
            } else if (colbase >= kcol0 && colbase < kcol1) {
                int hc = colbase - kcol0;
                int hh = hc >> 6, ebase = hc & 63;
                int tok = row;
                int es = (((ebase >> 3) ^ (tok & 7)) << 3) | (ebase & 7);
                bf16x4 pv;
#pragma unroll
                for (int r = 0; r < 4; r++) pv[r] = (__bf16)v[r];
                *(bf16x4*)&Cb[(size_t)tok * ldc + kcol0 + hh * 64 + es] = pv;
            } else {
                __bf16* dst = Cb + (size_t)kz * PART_STRIDE;
                bf16x4 pv;
#pragma unroll
                for (int r = 0; r < 4; r++) pv[r] = (__bf16)v[r];
                *(bf16x4*)&dst[(size_t)row * ldc + colbase] = pv;
            }
        }
    }
}

template <int LDA, int LDB>
__global__ __launch_bounds__(256) void mfma_gemm_bt(
    const __bf16* __restrict__ A,
    const __bf16* __restrict__ Bt,
    const float* __restrict__ bias,
    __bf16* __restrict__ Cb, int ldc,
    int Kc, int act, int qlimit,
    __bf16* __restrict__ VTout, int vtok, int vcol0, int kcol0, int kcol1,
    float* __restrict__ Xres) {
    __shared__ __bf16 As[128 * 64];   // 16 KiB
    __shared__ __bf16 Bs[128 * 64];   // 16 KiB
    // bijective XCD grouping swizzle (requires nwg%8==0; true for all grids)
    int gx = gridDim.x;
    int nwg = gx * gridDim.y;
    int orig = blockIdx.y * gx + blockIdx.x;
    int swz = (orig & 7) * (nwg >> 3) + (orig >> 3);
    gemm_body<LDA, LDB>(swz % gx, swz / gx, blockIdx.z, threadIdx.x,
                        A, Bt, bias, Cb, ldc, Kc, act, qlimit,
                        VTout, vtok, vcol0, kcol0, kcol1, Xres, As, Bs);
}

// ---------------- merged cross-attn GEMMs: Qc (384 blks) + KVc (192 blks) --
__global__ __launch_bounds__(256) void cross_gemm_kernel(
    const __bf16* __restrict__ LNb, const __bf16* __restrict__ cWt,
    const float* __restrict__ cbp, const __bf16* __restrict__ ctxb,
    __bf16* __restrict__ Qc, __bf16* __restrict__ KVc,
    __bf16* __restrict__ VTc) {
    __shared__ __bf16 As[128 * 64];
    __shared__ __bf16 Bs[128 * 64];
    int bid = blockIdx.x;
    if (bid < 384) {
        // Qc: M=8192 N=768 K=768, grid 6x64, XCD swizzle within range
        int swz = (bid & 7) * 48 + (bid >> 3);
        gemm_body<768, 768>(swz % 6, swz / 6, 0, threadIdx.x,
                            LNb, cWt, cbp, Qc, 768, D_EMB, 0, 768,
                            nullptr, 0, BIGCOL, BIGCOL, BIGCOL, nullptr, As, Bs);
    } else {
        // KVc: M=2048 N=1536 K=768, grid 12x16 ((bid-384)%8 == bid%8, 384%8==0)
        int b2 = bid - 384;
        int swz = (b2 & 7) * 24 + (b2 >> 3);
        gemm_body<768, 768>(swz % 12, swz / 12, 0, threadIdx.x,
                            ctxb, cWt + (size_t)768 * 768, cbp + 768,
                            KVc, 1536, D_EMB, 0, 0,
                            VTc, ROWS_CTX, 768, 0, 768, nullptr, As, Bs);
    }
}

// ---------------- flash MFMA attention, 128 q/block ------------------------
// T14 async-STAGE (r18, verified) + T5 setprio around MFMA clusters.
// 2 barriers/tile; block mapping XCD-grouped: bh = n%96, qt = n/96.
// Xin: if non-null, X[i] = Xin[i] + O (first residual); else X[i] += O.
__global__ __launch_bounds__(128, 2) void mfma_attn(
    const __bf16* __restrict__ Q, int qld,
    const __bf16* __restrict__ Kp, int kld,
    const __bf16* __restrict__ VTg, int vtok,
    int kv_tokens, float* __restrict__ X, const float* __restrict__ Xin) {
    __shared__ __bf16 Kt[64 * 64];     // [s][d] swizzled granules
    __shared__ __bf16 VT[80 * 64];     // [e][s] swizzled; rows 64..79 ones/zeros
    __shared__ __bf16 Ps[128 * 76];    // [q][s] stride 76; also Q staging (stride 64)
    int tid = threadIdx.x;
    int bh = blockIdx.x % 96;          // XCD-grouping: n%8 == bh%8
    int qt = blockIdx.x / 96;
    int b = bh / N_HEADS, h = bh - b * N_HEADS;
    int w = tid >> 6, lane = tid & 63, c = lane & 15, quad = lane >> 4;
    int q0 = qt * 128;

    for (int i = tid; i < 16 * 64; i += 128)
        VT[64 * 64 + i] = (i < 64) ? (__bf16)1.0f : (__bf16)0.0f;

    // per-thread K/V global bases (identical addresses to old gld16 path)
    const __bf16* Kg = Kp + (size_t)(b * kv_tokens + (tid >> 3)) * kld
                       + h * HEAD + (tid & 7) * 8;
    const __bf16* Vg = VTg + (size_t)(h * HEAD + (tid >> 3)) * vtok
                       + b * kv_tokens + (tid & 7) * 8;
    bf16x8 kr[4], vr[4], krn[4], vrn[4];
#pragma unroll
    for (int j = 0; j < 4; j++) {        // tile 0 prefetch (covered by Q stage)
        kr[j] = *(const bf16x8*)(Kg + (size_t)(j * 16) * kld);
        vr[j] = *(const bf16x8*)(Vg + (size_t)(j * 16) * vtok);
    }

    {
        const __bf16* Qg = Q + (size_t)(b * T_IMG + q0 + (tid >> 3)) * qld
                           + h * HEAD + (tid & 7) * 8;
        char* QsB = (char*)Ps + w * 1024;
#pragma unroll
        for (int j = 0; j < 8; j++)
            gld16(Qg + (size_t)j * 16 * qld, QsB + j * 2048);
    }
    __syncthreads();
    bf16x8 qa[4][2];
#pragma unroll
    for (int st = 0; st < 4; st++)
#pragma unroll
        for (int ch = 0; ch < 2; ch++)
            qa[st][ch] = *(const bf16x8*)&Ps[(w * 64 + st * 16 + c) * 64 + ch * 32 + quad * 8];

    f32x4 o[4][5];
#pragma unroll
    for (int st = 0; st < 4; st++)
#pragma unroll
        for (int ut = 0; ut < 5; ut++) o[st][ut] = (f32x4){0.f, 0.f, 0.f, 0.f};

    int ntiles = kv_tokens >> 6;
    for (int t = 0; t < ntiles; t++) {
        __syncthreads();   // (A) LDS free (prev PV + Q-frag reads drained);
                           //     also completes the in-flight kr/vr loads
#pragma unroll
        for (int j = 0; j < 4; j++) {
            *(bf16x8*)&Kt[tid * 8 + j * 1024] = kr[j];
            *(bf16x8*)&VT[tid * 8 + j * 1024] = vr[j];
        }
        __syncthreads();   // (B) K/V visible to both waves
        if (t + 1 < ntiles) {   // prefetch t+1: in flight until next (A)
            const __bf16* Kg2 = Kg + (size_t)((t + 1) * 64) * kld;
            const __bf16* Vg2 = Vg + (t + 1) * 64;
#pragma unroll
            for (int j = 0; j < 4; j++) {
                krn[j] = *(const bf16x8*)(Kg2 + (size_t)(j * 16) * kld);
                vrn[j] = *(const bf16x8*)(Vg2 + (size_t)(j * 16) * vtok);
            }
        }

        bf16x8 kb[4][2];
#pragma unroll
        for (int nt = 0; nt < 4; nt++)
#pragma unroll
            for (int ch = 0; ch < 2; ch++)
                kb[nt][ch] = *(const bf16x8*)&Kt[(nt * 16 + c) * 64
                                + (((ch * 4 + quad) ^ (c & 7)) << 3)];
#pragma unroll
        for (int st = 0; st < 4; st++) {
            f32x4 s[4];
            __builtin_amdgcn_s_setprio(1);
#pragma unroll
            for (int nt = 0; nt < 4; nt++) {
                s[nt] = (f32x4){0.f, 0.f, 0.f, 0.f};
                s[nt] = __builtin_amdgcn_mfma_f32_16x16x32_bf16(kb[nt][0], qa[st][0], s[nt], 0, 0, 0);
                s[nt] = __builtin_amdgcn_mfma_f32_16x16x32_bf16(kb[nt][1], qa[st][1], s[nt], 0, 0, 0);
            }
            __builtin_amdgcn_s_setprio(0);
#pragma unroll
            for (int nt = 0; nt < 4; nt++) {
                bf16x4 pk;
#pragma unroll
                for (int r = 0; r < 4; r++) pk[r] = (__bf16)__expf(s[nt][r]);
                *(bf16x4*)&Ps[(size_t)(w * 64 + st * 16 + c) * 76 + nt * 16 + quad * 4] = pk;
            }
        }
        // NO barrier: P rows [w*64, w*64+64) are written and read by the SAME
        // wave only -> compiler-ordered via lgkmcnt (in-order DS ops).

        bf16x8 vb[5][2];
#pragma unroll
        for (int ut = 0; ut < 5; ut++)
#pragma unroll
            for (int ch = 0; ch < 2; ch++)
                vb[ut][ch] = *(const bf16x8*)&VT[(ut * 16 + c) * 64
                                + (((ch * 4 + quad) ^ (c & 7)) << 3)];
#pragma unroll
        for (int st = 0; st < 4; st++) {
            bf16x8 pa0 = *(const bf16x8*)&Ps[(w * 64 + st * 16 + c) * 76 + quad * 8];
            bf16x8 pa1 = *(const bf16x8*)&Ps[(w * 64 + st * 16 + c) * 76 + 32 + quad * 8];
            __builtin_amdgcn_s_setprio(1);
#pragma unroll
            for (int ut = 0; ut < 5; ut++) {
                o[st][ut] = __builtin_amdgcn_mfma_f32_16x16x32_bf16(pa0, vb[ut][0], o[st][ut], 0, 0, 0);
                o[st][ut] = __builtin_amdgcn_mfma_f32_16x16x32_bf16(pa1, vb[ut][1], o[st][ut], 0, 0, 0);
            }
            __builtin_amdgcn_s_setprio(0);
        }
        if (t + 1 < ntiles) {
#pragma unroll
            for (int j = 0; j < 4; j++) { kr[j] = krn[j]; vr[j] = vrn[j]; }
        }
    }

#pragma unroll
    for (int st = 0; st < 4; st++) {
        float lr[4];
#pragma unroll
        for (int r = 0; r < 4; r++) lr[r] = __shfl(o[st][4][r], lane & 48, 64);
#pragma unroll
        for (int ut = 0; ut < 4; ut++) {
#pragma unroll
            for (int r = 0; r < 4; r++) {
                int row = b * T_IMG + q0 + w * 64 + st * 16 + quad * 4 + r;
                int col = h * HEAD + ut * 16 + c;
                size_t idx = (size_t)row * D_EMB + col;
                float base = Xin ? Xin[idx] : X[idx];
                X[idx] = base + o[st][ut][r] / lr[r];
            }
        }
    }
}

// ---------------------------------------------------------------------------
extern "C" void kernel_launch(void* const* d_in, const int* in_sizes, int n_in,
                              void* d_out, int out_size, void* d_ws, size_t ws_size,
                              hipStream_t stream) {
    const float* img  = (const float*)d_in[0];
    const float* ctx  = (const float*)d_in[1];
    const float* ln1w = (const float*)d_in[2];  const float* ln1b = (const float*)d_in[3];
    const float* sWq  = (const float*)d_in[4];  const float* sbq  = (const float*)d_in[5];
    const float* sWk  = (const float*)d_in[6];  const float* sbk  = (const float*)d_in[7];
    const float* sWv  = (const float*)d_in[8];  const float* sbv  = (const float*)d_in[9];
    const float* ln2w = (const float*)d_in[10]; const float* ln2b = (const float*)d_in[11];
    const float* cWq  = (const float*)d_in[12]; const float* cbq  = (const float*)d_in[13];
    const float* cWk  = (const float*)d_in[14]; const float* cbk  = (const float*)d_in[15];
    const float* cWv  = (const float*)d_in[16]; const float* cbv  = (const float*)d_in[17];
    const float* ln3w = (const float*)d_in[18]; const float* ln3b = (const float*)d_in[19];
    const float* W1   = (const float*)d_in[20]; const float* b1   = (const float*)d_in[21];
    const float* W2   = (const float*)d_in[22]; const float* b2   = (const float*)d_in[23];

    float* X = (float*)d_out;

    char* p = (char*)d_ws;
    __bf16* LNb  = (__bf16*)p; p += (size_t)ROWS_IMG * D_EMB * 2;       // 12.6 MB
    __bf16* VTg  = (__bf16*)p; p += (size_t)12 * 64 * ROWS_IMG * 2;     // 12.6 MB
    __bf16* BIG  = (__bf16*)p; p += (size_t)ROWS_IMG * FF_DIM * 2;      // 50.3 MB
    __bf16* ctxb = (__bf16*)p; p += (size_t)ROWS_CTX * D_EMB * 2;       // 3.1 MB
    __bf16* Wt   = (__bf16*)p; p += (size_t)2304 * 768 * 2;             // 3.5 MB
    __bf16* cWt  = (__bf16*)p; p += (size_t)2304 * 768 * 2;             // 3.5 MB
    __bf16* W1t  = (__bf16*)p; p += (size_t)FF_DIM * 768 * 2;           // 4.7 MB
    __bf16* W2t  = (__bf16*)p; p += (size_t)768 * FF_DIM * 2;           // 4.7 MB
    __bf16* VTc  = (__bf16*)p; p += (size_t)12 * 64 * ROWS_CTX * 2;     // 3.1 MB
    float*  bp   = (float*)p;  p += 2304 * 4;
    float*  cbp  = (float*)p;  p += 2304 * 4;
    __bf16* Pk   = LNb;   // split-K partials overlay (LNb+VTg dead by stage 3)
    __bf16* QKVb = BIG;
    __bf16* Qc   = BIG;
    __bf16* KVc  = BIG + (size_t)ROWS_IMG * 768;          // r18 location (sequential)
    __bf16* FFh  = BIG;

    // ---- all preprocessing + ln1 in ONE dispatch ----
    preproc_kernel<<<11744, 256, 0, stream>>>(
        ctx, ctxb,
        sWq, sWk, sWv, sbq, sbk, sbv, Wt, bp,
        cWq, cWk, cWv, cbq, cbk, cbv, cWt, cbp,
        W1, W1t, W2, W2t,
        img, ln1w, ln1b, LNb);

    // ---- stage 1: self attention (attn1 fuses X = img + O) ----
    mfma_gemm_bt<768, 768><<<dim3(2304 / 128, ROWS_IMG / 128), 256, 0, stream>>>(
        LNb, Wt, bp, QKVb, 2304, D_EMB, 0, 768,
        VTg, ROWS_IMG, 1536, 768, 1536, nullptr);
    mfma_attn<<<96 * 8, 128, 0, stream>>>(
        QKVb, 2304, QKVb + 768, 2304, VTg, ROWS_IMG, T_IMG, X, img);

    // ---- stage 2: cross attention (Qc + KVc in ONE dispatch) ----
    ln_kernel<<<ROWS_IMG, 256, 0, stream>>>(X, ln2w, ln2b, LNb);
    cross_gemm_kernel<<<576, 256, 0, stream>>>(LNb, cWt, cbp, ctxb, Qc, KVc, VTc);
    mfma_attn<<<96 * 8, 128, 0, stream>>>(
        Qc, 768, KVc, 1536, VTc, ROWS_CTX, T_CTX, X, nullptr);

    // ---- stage 3: MLP (W1 single pass; W2 split-K x2 + fused reduce) ----
    ln_kernel<<<ROWS_IMG, 256, 0, stream>>>(X, ln3w, ln3b, LNb);
    mfma_gemm_bt<768, 768><<<dim3(FF_DIM / 128, ROWS_IMG / 128), 256, 0, stream>>>(
        LNb, W1t, b1, FFh, FF_DIM, D_EMB, 1, 0,
        nullptr, 0, BIGCOL, BIGCOL, BIGCOL, nullptr);
    mfma_gemm_bt<3072, 3072><<<dim3(768 / 128, ROWS_IMG / 128, 2), 256, 0, stream>>>(
        FFh, W2t, nullptr, Pk, D_EMB, 1536, 0, 0,
        nullptr, 0, BIGCOL, BIGCOL, BIGCOL, nullptr);
    reduce_w2_kernel<<<ROWS_IMG * D_EMB / 4 / 256, 256, 0, stream>>>(Pk, b2, X);
}